// Round 1
// baseline (759.462 us; speedup 1.0000x reference)
//
#include <hip/hip_runtime.h>
#include <hip/hip_bf16.h>

#define T_TOK 4096
#define HDIM 1024
#define IDIM 1024
#define EDIM 8

typedef __attribute__((ext_vector_type(8))) short bf16x8;
typedef __attribute__((ext_vector_type(4))) float f32x4;

static __device__ __forceinline__ unsigned short f2bf(float f) {
  union { float f; unsigned int u; } v; v.f = f;
  unsigned int u = v.u;
  unsigned int r = u + 0x7FFFu + ((u >> 16) & 1u);   // RTNE
  return (unsigned short)(r >> 16);
}

// ---------------- x fp32 -> bf16 ----------------
__global__ __launch_bounds__(256) void convert_x(const float4* __restrict__ x4,
                                                 ushort4* __restrict__ xb4) {
  int i = blockIdx.x * 256 + threadIdx.x;
  float4 v = x4[i];
  ushort4 o;
  o.x = f2bf(v.x); o.y = f2bf(v.y); o.z = f2bf(v.z); o.w = f2bf(v.w);
  xb4[i] = o;
}

// ---------------- zero counts ----------------
__global__ void zero_cnt(int* __restrict__ cnt) {
  if (threadIdx.x < 16) cnt[threadIdx.x] = 0;
}

// ---------------- router + top-2 + expert lists ----------------
__global__ __launch_bounds__(64) void router_topk(
    const float* __restrict__ x, const float* __restrict__ rw,
    int* __restrict__ cnt, int* __restrict__ list, float* __restrict__ wgt) {
  const int t = blockIdx.x;
  const int lane = threadIdx.x;
  const float* xr = x + (size_t)t * HDIM;
  float xv[16];
#pragma unroll
  for (int i = 0; i < 16; i++) xv[i] = xr[lane + 64 * i];
  float l[EDIM];
#pragma unroll
  for (int e = 0; e < EDIM; e++) {
    const float* wr = rw + (size_t)e * HDIM;
    float a = 0.f;
#pragma unroll
    for (int i = 0; i < 16; i++) a += xv[i] * wr[lane + 64 * i];
#pragma unroll
    for (int s = 32; s > 0; s >>= 1) a += __shfl_xor(a, s, 64);
    l[e] = a;
  }
  if (lane == 0) {
    float m = l[0];
#pragma unroll
    for (int e = 1; e < EDIM; e++) m = fmaxf(m, l[e]);
    float p[EDIM]; float s = 0.f;
#pragma unroll
    for (int e = 0; e < EDIM; e++) { p[e] = expf(l[e] - m); s += p[e]; }
    float inv = 1.f / s;
    int e1 = 0; float b1 = p[0];
#pragma unroll
    for (int e = 1; e < EDIM; e++) if (p[e] > b1) { b1 = p[e]; e1 = e; }
    int e2 = -1; float b2 = -1.f;
#pragma unroll
    for (int e = 0; e < EDIM; e++) if (e != e1 && p[e] > b2) { b2 = p[e]; e2 = e; }
    int pos1 = atomicAdd(&cnt[e1], 1);
    list[e1 * T_TOK + pos1] = t; wgt[e1 * T_TOK + pos1] = b1 * inv;
    int pos2 = atomicAdd(&cnt[e2], 1);
    list[e2 * T_TOK + pos2] = t; wgt[e2 * T_TOK + pos2] = b2 * inv;
  }
}

// ---------------- gate/up GEMM: hid = sigmoid(X Wg) * (X Wu)  (bf16 out) ----
// BM=128, BN=64, BK=32. Block 256 thr (4 waves in 2x2). Wave tile 64x32.
template <bool GATHER>
__global__ __launch_bounds__(256) void gateup_gemm(
    const unsigned short* __restrict__ xb,
    const float* __restrict__ Wg_, const float* __restrict__ Wu_,
    unsigned short* __restrict__ hid,
    const int* __restrict__ cnt, const int* __restrict__ list) {
  constexpr int PK = 40;  // padded K stride (elements); 80B rows, 16B aligned
  __shared__ unsigned short Al[128 * PK];
  __shared__ unsigned short Bg[64 * PK];
  __shared__ unsigned short Bu[64 * PK];

  const int tid = threadIdx.x;
  const int lane = tid & 63;
  const int wv = tid >> 6;
  const int wm = wv >> 1, wn = wv & 1;

  int count, hidbase, e = 0;
  const float *wg, *wu;
  if constexpr (GATHER) {
    e = blockIdx.z;
    count = cnt[e];
    if ((int)blockIdx.y * 128 >= count) return;
    int off = 0;
#pragma unroll
    for (int i = 0; i < EDIM; i++) off += (i < e) ? cnt[i] : 0;
    hidbase = off;
    wg = Wg_ + (size_t)e * HDIM * IDIM;
    wu = Wu_ + (size_t)e * HDIM * IDIM;
  } else {
    count = T_TOK; hidbase = 0; wg = Wg_; wu = Wu_;
  }
  const int m0 = blockIdx.y * 128;
  const int n0 = blockIdx.x * 64;

  // A staging: 2 rows x 8 bf16 per thread
  const int ar0 = tid >> 2;
  const int ar1 = ar0 + 64;
  const int ak8 = (tid & 3) * 8;
  int tok0, tok1;
  if constexpr (GATHER) {
    int p0 = m0 + ar0; if (p0 >= count) p0 = count - 1;
    int p1 = m0 + ar1; if (p1 >= count) p1 = count - 1;
    tok0 = list[e * T_TOK + p0];
    tok1 = list[e * T_TOK + p1];
  } else {
    tok0 = m0 + ar0; tok1 = m0 + ar1;
  }
  const unsigned short* a0 = xb + (size_t)tok0 * HDIM + ak8;
  const unsigned short* a1 = xb + (size_t)tok1 * HDIM + ak8;

  // B staging: thread -> n = tid&63, k-pair base = (tid>>6)*2
  const int bn = tid & 63;
  const int bk0 = (tid >> 6) * 2;

  f32x4 accg[4][2], accu[4][2];
  const f32x4 z4 = {0.f, 0.f, 0.f, 0.f};
#pragma unroll
  for (int i = 0; i < 4; i++)
#pragma unroll
    for (int j = 0; j < 2; j++) { accg[i][j] = z4; accu[i][j] = z4; }

  for (int k0 = 0; k0 < HDIM; k0 += 32) {
    *(bf16x8*)&Al[ar0 * PK + ak8] = *(const bf16x8*)(a0 + k0);
    *(bf16x8*)&Al[ar1 * PK + ak8] = *(const bf16x8*)(a1 + k0);
#pragma unroll
    for (int kk = bk0; kk < 32; kk += 8) {
      const float* pg = wg + (size_t)(k0 + kk) * IDIM + n0 + bn;
      const float* pu = wu + (size_t)(k0 + kk) * IDIM + n0 + bn;
      float g0 = pg[0], g1 = pg[IDIM];
      float u0 = pu[0], u1 = pu[IDIM];
      *(unsigned int*)&Bg[bn * PK + kk] =
          (unsigned int)f2bf(g0) | ((unsigned int)f2bf(g1) << 16);
      *(unsigned int*)&Bu[bn * PK + kk] =
          (unsigned int)f2bf(u0) | ((unsigned int)f2bf(u1) << 16);
    }
    __syncthreads();
    const int q = lane >> 4;
    const int r16 = lane & 15;
    bf16x8 af[4], bfg[2], bfu[2];
#pragma unroll
    for (int i = 0; i < 4; i++)
      af[i] = *(const bf16x8*)&Al[(wm * 64 + i * 16 + r16) * PK + q * 8];
#pragma unroll
    for (int j = 0; j < 2; j++) {
      bfg[j] = *(const bf16x8*)&Bg[(wn * 32 + j * 16 + r16) * PK + q * 8];
      bfu[j] = *(const bf16x8*)&Bu[(wn * 32 + j * 16 + r16) * PK + q * 8];
    }
#pragma unroll
    for (int i = 0; i < 4; i++)
#pragma unroll
      for (int j = 0; j < 2; j++) {
        accg[i][j] = __builtin_amdgcn_mfma_f32_16x16x32_bf16(af[i], bfg[j], accg[i][j], 0, 0, 0);
        accu[i][j] = __builtin_amdgcn_mfma_f32_16x16x32_bf16(af[i], bfu[j], accu[i][j], 0, 0, 0);
      }
    __syncthreads();
  }

  const int q = lane >> 4;
  const int c16 = lane & 15;
#pragma unroll
  for (int i = 0; i < 4; i++) {
#pragma unroll
    for (int j = 0; j < 2; j++) {
      const int col = n0 + wn * 32 + j * 16 + c16;
#pragma unroll
      for (int r = 0; r < 4; r++) {
        int pos = m0 + wm * 64 + i * 16 + q * 4 + r;
        bool ok = GATHER ? (pos < count) : true;
        if (ok) {
          float g = accg[i][j][r], u = accu[i][j][r];
          float h = u / (1.f + __expf(-g));
          hid[(size_t)(hidbase + pos) * IDIM + col] = f2bf(h);
        }
      }
    }
  }
}

// ---------------- down GEMM ----------------
// BM=128, BN=128, BK=32. shared: out = resid + acc. routed: atomicAdd(w*acc).
template <bool ROUTED>
__global__ __launch_bounds__(256) void down_gemm(
    const unsigned short* __restrict__ hidin,
    const float* __restrict__ Wd_,
    float* __restrict__ out, const float* __restrict__ resid,
    const int* __restrict__ cnt, const int* __restrict__ list,
    const float* __restrict__ wgt) {
  constexpr int PK = 40;
  __shared__ unsigned short Al[128 * PK];
  __shared__ unsigned short Bl[128 * PK];

  const int tid = threadIdx.x;
  const int lane = tid & 63;
  const int wv = tid >> 6;
  const int wm = wv >> 1, wn = wv & 1;

  int count, abase, e = 0;
  const float* wd;
  if constexpr (ROUTED) {
    e = blockIdx.z;
    count = cnt[e];
    if ((int)blockIdx.y * 128 >= count) return;
    int off = 0;
#pragma unroll
    for (int i = 0; i < EDIM; i++) off += (i < e) ? cnt[i] : 0;
    abase = off;
    wd = Wd_ + (size_t)e * IDIM * HDIM;
  } else {
    count = T_TOK; abase = 0; wd = Wd_;
  }
  const int m0 = blockIdx.y * 128;
  const int n0 = blockIdx.x * 128;

  const int ar0 = tid >> 2, ar1 = ar0 + 64, ak8 = (tid & 3) * 8;
  const unsigned short* a0 = hidin + (size_t)(abase + m0 + ar0) * IDIM + ak8;
  const unsigned short* a1 = hidin + (size_t)(abase + m0 + ar1) * IDIM + ak8;

  const int bn = tid & 127;
  const int bk0 = (tid >> 7) * 2;

  f32x4 acc[4][4];
  const f32x4 z4 = {0.f, 0.f, 0.f, 0.f};
#pragma unroll
  for (int i = 0; i < 4; i++)
#pragma unroll
    for (int j = 0; j < 4; j++) acc[i][j] = z4;

  for (int k0 = 0; k0 < IDIM; k0 += 32) {
    *(bf16x8*)&Al[ar0 * PK + ak8] = *(const bf16x8*)(a0 + k0);
    *(bf16x8*)&Al[ar1 * PK + ak8] = *(const bf16x8*)(a1 + k0);
#pragma unroll
    for (int kk = bk0; kk < 32; kk += 4) {
      const float* pb = wd + (size_t)(k0 + kk) * HDIM + n0 + bn;
      float b0 = pb[0], b1 = pb[HDIM];
      *(unsigned int*)&Bl[bn * PK + kk] =
          (unsigned int)f2bf(b0) | ((unsigned int)f2bf(b1) << 16);
    }
    __syncthreads();
    const int q = lane >> 4;
    const int r16 = lane & 15;
    bf16x8 af[4], bf[4];
#pragma unroll
    for (int i = 0; i < 4; i++)
      af[i] = *(const bf16x8*)&Al[(wm * 64 + i * 16 + r16) * PK + q * 8];
#pragma unroll
    for (int j = 0; j < 4; j++)
      bf[j] = *(const bf16x8*)&Bl[(wn * 64 + j * 16 + r16) * PK + q * 8];
#pragma unroll
    for (int i = 0; i < 4; i++)
#pragma unroll
      for (int j = 0; j < 4; j++)
        acc[i][j] = __builtin_amdgcn_mfma_f32_16x16x32_bf16(af[i], bf[j], acc[i][j], 0, 0, 0);
    __syncthreads();
  }

  const int q = lane >> 4;
  const int c16 = lane & 15;
#pragma unroll
  for (int i = 0; i < 4; i++) {
    int toks[4]; float ws4[4];
#pragma unroll
    for (int r = 0; r < 4; r++) {
      int pos = m0 + wm * 64 + i * 16 + q * 4 + r;
      if constexpr (ROUTED) {
        bool ok = pos < count;
        toks[r] = ok ? list[e * T_TOK + pos] : -1;
        ws4[r] = ok ? wgt[e * T_TOK + pos] : 0.f;
      } else {
        toks[r] = pos; ws4[r] = 1.f;
      }
    }
#pragma unroll
    for (int j = 0; j < 4; j++) {
      const int col = n0 + wn * 64 + j * 16 + c16;
#pragma unroll
      for (int r = 0; r < 4; r++) {
        if constexpr (ROUTED) {
          if (toks[r] >= 0)
            atomicAdd(&out[(size_t)toks[r] * HDIM + col], ws4[r] * acc[i][j][r]);
        } else {
          size_t idx = (size_t)toks[r] * HDIM + col;
          out[idx] = resid[idx] + acc[i][j][r];
        }
      }
    }
  }
}

extern "C" void kernel_launch(void* const* d_in, const int* in_sizes, int n_in,
                              void* d_out, int out_size, void* d_ws, size_t ws_size,
                              hipStream_t stream) {
  const float* x  = (const float*)d_in[0];
  const float* rw = (const float*)d_in[1];
  const float* sg = (const float*)d_in[2];
  const float* su = (const float*)d_in[3];
  const float* sd = (const float*)d_in[4];
  const float* eg = (const float*)d_in[5];
  const float* eu = (const float*)d_in[6];
  const float* ed = (const float*)d_in[7];
  float* out = (float*)d_out;

  char* ws = (char*)d_ws;
  unsigned short* xb   = (unsigned short*)ws;                       // 4096*1024 bf16
  unsigned short* shid = xb + (size_t)T_TOK * HDIM;                 // 4096*1024 bf16
  unsigned short* rhid = shid + (size_t)T_TOK * IDIM;               // (8192+128)*1024 bf16
  int*   cnt  = (int*)(rhid + (size_t)(T_TOK * 2 + 128) * IDIM);
  int*   list = cnt + 16;
  float* wgt  = (float*)(list + EDIM * T_TOK);

  zero_cnt<<<1, 64, 0, stream>>>(cnt);
  convert_x<<<(T_TOK * HDIM) / 1024, 256, 0, stream>>>((const float4*)x, (ushort4*)xb);
  router_topk<<<T_TOK, 64, 0, stream>>>(x, rw, cnt, list, wgt);

  // shared expert
  gateup_gemm<false><<<dim3(IDIM / 64, T_TOK / 128, 1), 256, 0, stream>>>(
      xb, sg, su, shid, nullptr, nullptr);
  // routed experts (early-exit blocks beyond per-expert count)
  gateup_gemm<true><<<dim3(IDIM / 64, T_TOK / 128, EDIM), 256, 0, stream>>>(
      xb, eg, eu, rhid, cnt, list);

  // shared down writes out = residual + shared_out
  down_gemm<false><<<dim3(HDIM / 128, T_TOK / 128, 1), 256, 0, stream>>>(
      shid, sd, out, x, nullptr, nullptr, nullptr);
  // routed down accumulates weighted expert outputs
  down_gemm<true><<<dim3(HDIM / 128, T_TOK / 128, EDIM), 256, 0, stream>>>(
      rhid, ed, out, nullptr, cnt, list, wgt);
}

// Round 2
// 466.549 us; speedup vs baseline: 1.6278x; 1.6278x over previous
//
#include <hip/hip_runtime.h>
#include <hip/hip_bf16.h>

#define T_TOK 4096
#define HDIM 1024
#define IDIM 1024
#define EDIM 8

typedef __attribute__((ext_vector_type(8))) short bf16x8;
typedef __attribute__((ext_vector_type(4))) float f32x4;

static __device__ __forceinline__ unsigned short f2bf(float f) {
  union { float f; unsigned int u; } v; v.f = f;
  unsigned int u = v.u;
  unsigned int r = u + 0x7FFFu + ((u >> 16) & 1u);   // RTNE
  return (unsigned short)(r >> 16);
}

// async global->LDS, 16B per lane; lds base must be wave-uniform
#define GLD16(g, l) __builtin_amdgcn_global_load_lds( \
    (const __attribute__((address_space(1))) void*)(g), \
    (__attribute__((address_space(3))) void*)(l), 16, 0, 0)

// ---------------- x fp32 -> bf16 ----------------
__global__ __launch_bounds__(256) void convert_x(const float4* __restrict__ x4,
                                                 ushort4* __restrict__ xb4) {
  int i = blockIdx.x * 256 + threadIdx.x;
  float4 v = x4[i];
  ushort4 o;
  o.x = f2bf(v.x); o.y = f2bf(v.y); o.z = f2bf(v.z); o.w = f2bf(v.w);
  xb4[i] = o;
}

// ---------------- weight fp32 [B][K][N] -> bf16 [B][N][K] ----------------
__global__ __launch_bounds__(256) void transpose_w(const float* __restrict__ src,
                                                   unsigned short* __restrict__ dst) {
  __shared__ unsigned short t[32][36];
  const int b = blockIdx.z;
  const int r0 = blockIdx.y * 32;   // K base
  const int c0 = blockIdx.x * 32;   // N base
  const int tid = threadIdx.x;
  const int rr = tid >> 3;          // 0..31
  const int cc = (tid & 7) * 4;     // 0,4,..,28
  const float4 v = *(const float4*)&src[((size_t)b * 1024 + r0 + rr) * 1024 + c0 + cc];
  t[rr][cc + 0] = f2bf(v.x); t[rr][cc + 1] = f2bf(v.y);
  t[rr][cc + 2] = f2bf(v.z); t[rr][cc + 3] = f2bf(v.w);
  __syncthreads();
  const int n = rr;                 // output row within tile (orig col)
  const int k4 = cc;                // 4 orig rows
  ushort4 o;
  o.x = t[k4 + 0][n]; o.y = t[k4 + 1][n]; o.z = t[k4 + 2][n]; o.w = t[k4 + 3][n];
  *(ushort4*)&dst[((size_t)b * 1024 + c0 + n) * 1024 + r0 + k4] = o;
}

// ---------------- zero counts ----------------
__global__ void zero_cnt(int* __restrict__ cnt) {
  if (threadIdx.x < 16) cnt[threadIdx.x] = 0;
}

// ---------------- router + top-2 + expert lists ----------------
__global__ __launch_bounds__(64) void router_topk(
    const float* __restrict__ x, const float* __restrict__ rw,
    int* __restrict__ cnt, int* __restrict__ list, float* __restrict__ wgt) {
  const int t = blockIdx.x;
  const int lane = threadIdx.x;
  const float* xr = x + (size_t)t * HDIM;
  float xv[16];
#pragma unroll
  for (int i = 0; i < 16; i++) xv[i] = xr[lane + 64 * i];
  float l[EDIM];
#pragma unroll
  for (int e = 0; e < EDIM; e++) {
    const float* wr = rw + (size_t)e * HDIM;
    float a = 0.f;
#pragma unroll
    for (int i = 0; i < 16; i++) a += xv[i] * wr[lane + 64 * i];
#pragma unroll
    for (int s = 32; s > 0; s >>= 1) a += __shfl_xor(a, s, 64);
    l[e] = a;
  }
  if (lane == 0) {
    float m = l[0];
#pragma unroll
    for (int e = 1; e < EDIM; e++) m = fmaxf(m, l[e]);
    float p[EDIM]; float s = 0.f;
#pragma unroll
    for (int e = 0; e < EDIM; e++) { p[e] = expf(l[e] - m); s += p[e]; }
    float inv = 1.f / s;
    int e1 = 0; float b1 = p[0];
#pragma unroll
    for (int e = 1; e < EDIM; e++) if (p[e] > b1) { b1 = p[e]; e1 = e; }
    int e2 = -1; float b2 = -1.f;
#pragma unroll
    for (int e = 0; e < EDIM; e++) if (e != e1 && p[e] > b2) { b2 = p[e]; e2 = e; }
    int pos1 = atomicAdd(&cnt[e1], 1);
    list[e1 * T_TOK + pos1] = t; wgt[e1 * T_TOK + pos1] = b1 * inv;
    int pos2 = atomicAdd(&cnt[e2], 1);
    list[e2 * T_TOK + pos2] = t; wgt[e2 * T_TOK + pos2] = b2 * inv;
  }
}

// ---------------- gate/up GEMM: hid = sigmoid(X WgT^t) * (X WuT^t) ----------
// BM=128, BN=64 (per matrix), BK=32. 256 thr = 4 waves (2x2). All operands
// bf16 k-major; staged with global_load_lds width=16.
template <bool GATHER>
__global__ __launch_bounds__(256) void gateup_gemm(
    const unsigned short* __restrict__ xb,
    const unsigned short* __restrict__ WgT_, const unsigned short* __restrict__ WuT_,
    unsigned short* __restrict__ hid,
    const int* __restrict__ cnt, const int* __restrict__ list) {
  __shared__ unsigned short Al[128 * 32];   // [row][k] 64B rows
  __shared__ unsigned short Bg[64 * 32];
  __shared__ unsigned short Bu[64 * 32];

  const int tid = threadIdx.x;
  const int lane = tid & 63;
  const int w = tid >> 6;
  const int wm = w >> 1, wn = w & 1;

  int count, hidbase, e = 0;
  const unsigned short *wg, *wu;
  if constexpr (GATHER) {
    e = blockIdx.z;
    count = cnt[e];
    if ((int)blockIdx.y * 128 >= count) return;
    int off = 0;
#pragma unroll
    for (int i = 0; i < EDIM; i++) off += (i < e) ? cnt[i] : 0;
    hidbase = off;
    wg = WgT_ + (size_t)e * HDIM * IDIM;
    wu = WuT_ + (size_t)e * HDIM * IDIM;
  } else {
    count = T_TOK; hidbase = 0; wg = WgT_; wu = WuT_;
  }
  const int m0 = blockIdx.y * 128;
  const int n0 = blockIdx.x * 64;

  // staging geometry: slot = 16B chunk; row = slot>>2, chunk = slot&3
  const int srow = (w * 64 + lane) >> 2;    // 0..63
  const int chunk = lane & 3;
  int tokA0, tokA1;
  if constexpr (GATHER) {
    int p0 = m0 + srow;      if (p0 >= count) p0 = count - 1;
    int p1 = m0 + srow + 64; if (p1 >= count) p1 = count - 1;
    tokA0 = list[e * T_TOK + p0];
    tokA1 = list[e * T_TOK + p1];
  } else {
    tokA0 = m0 + srow; tokA1 = m0 + srow + 64;
  }
  const unsigned short* ga0 = xb + (size_t)tokA0 * HDIM + chunk * 8;
  const unsigned short* ga1 = xb + (size_t)tokA1 * HDIM + chunk * 8;
  const unsigned short* gbg = wg + (size_t)(n0 + srow) * HDIM + chunk * 8;
  const unsigned short* gbu = wu + (size_t)(n0 + srow) * HDIM + chunk * 8;
  unsigned short* lA0 = &Al[(w * 64) * 8];
  unsigned short* lA1 = &Al[(256 + w * 64) * 8];
  unsigned short* lBg = &Bg[(w * 64) * 8];
  unsigned short* lBu = &Bu[(w * 64) * 8];

  f32x4 accg[4][2], accu[4][2];
  const f32x4 z4 = {0.f, 0.f, 0.f, 0.f};
#pragma unroll
  for (int i = 0; i < 4; i++)
#pragma unroll
    for (int j = 0; j < 2; j++) { accg[i][j] = z4; accu[i][j] = z4; }

  const int q = lane >> 4;
  const int r16 = lane & 15;

  for (int k0 = 0; k0 < HDIM; k0 += 32) {
    __syncthreads();
    GLD16(ga0 + k0, lA0);
    GLD16(ga1 + k0, lA1);
    GLD16(gbg + k0, lBg);
    GLD16(gbu + k0, lBu);
    __syncthreads();
    bf16x8 af[4], bg2[2], bu2[2];
#pragma unroll
    for (int i = 0; i < 4; i++)
      af[i] = *(const bf16x8*)&Al[(wm * 64 + i * 16 + r16) * 32 + q * 8];
#pragma unroll
    for (int j = 0; j < 2; j++) {
      bg2[j] = *(const bf16x8*)&Bg[(wn * 32 + j * 16 + r16) * 32 + q * 8];
      bu2[j] = *(const bf16x8*)&Bu[(wn * 32 + j * 16 + r16) * 32 + q * 8];
    }
#pragma unroll
    for (int i = 0; i < 4; i++)
#pragma unroll
      for (int j = 0; j < 2; j++) {
        accg[i][j] = __builtin_amdgcn_mfma_f32_16x16x32_bf16(af[i], bg2[j], accg[i][j], 0, 0, 0);
        accu[i][j] = __builtin_amdgcn_mfma_f32_16x16x32_bf16(af[i], bu2[j], accu[i][j], 0, 0, 0);
      }
  }

#pragma unroll
  for (int i = 0; i < 4; i++) {
#pragma unroll
    for (int j = 0; j < 2; j++) {
      const int col = n0 + wn * 32 + j * 16 + r16;
#pragma unroll
      for (int r = 0; r < 4; r++) {
        int pos = m0 + wm * 64 + i * 16 + q * 4 + r;
        bool ok = GATHER ? (pos < count) : true;
        if (ok) {
          float g = accg[i][j][r], u = accu[i][j][r];
          float h = u / (1.f + __expf(-g));
          hid[(size_t)(hidbase + pos) * IDIM + col] = f2bf(h);
        }
      }
    }
  }
}

// ---------------- down GEMM ----------------
// BM=128, BN=128, BK=32. shared: out = resid + acc. routed: atomicAdd(w*acc).
template <bool ROUTED>
__global__ __launch_bounds__(256) void down_gemm(
    const unsigned short* __restrict__ hidin,
    const unsigned short* __restrict__ WdT_,
    float* __restrict__ out, const float* __restrict__ resid,
    const int* __restrict__ cnt, const int* __restrict__ list,
    const float* __restrict__ wgt) {
  __shared__ unsigned short Al[128 * 32];
  __shared__ unsigned short Bl[128 * 32];

  const int tid = threadIdx.x;
  const int lane = tid & 63;
  const int w = tid >> 6;
  const int wm = w >> 1, wn = w & 1;

  int count, abase, e = 0;
  const unsigned short* wd;
  if constexpr (ROUTED) {
    e = blockIdx.z;
    count = cnt[e];
    if ((int)blockIdx.y * 128 >= count) return;
    int off = 0;
#pragma unroll
    for (int i = 0; i < EDIM; i++) off += (i < e) ? cnt[i] : 0;
    abase = off;
    wd = WdT_ + (size_t)e * IDIM * HDIM;
  } else {
    count = T_TOK; abase = 0; wd = WdT_;
  }
  const int m0 = blockIdx.y * 128;
  const int n0 = blockIdx.x * 128;

  const int srow = (w * 64 + lane) >> 2;
  const int chunk = lane & 3;
  const unsigned short* ga0 = hidin + (size_t)(abase + m0 + srow) * IDIM + chunk * 8;
  const unsigned short* ga1 = ga0 + (size_t)64 * IDIM;
  const unsigned short* gb0 = wd + (size_t)(n0 + srow) * IDIM + chunk * 8;
  const unsigned short* gb1 = gb0 + (size_t)64 * IDIM;
  unsigned short* lA0 = &Al[(w * 64) * 8];
  unsigned short* lA1 = &Al[(256 + w * 64) * 8];
  unsigned short* lB0 = &Bl[(w * 64) * 8];
  unsigned short* lB1 = &Bl[(256 + w * 64) * 8];

  f32x4 acc[4][4];
  const f32x4 z4 = {0.f, 0.f, 0.f, 0.f};
#pragma unroll
  for (int i = 0; i < 4; i++)
#pragma unroll
    for (int j = 0; j < 4; j++) acc[i][j] = z4;

  const int q = lane >> 4;
  const int r16 = lane & 15;

  for (int k0 = 0; k0 < IDIM; k0 += 32) {
    __syncthreads();
    GLD16(ga0 + k0, lA0);
    GLD16(ga1 + k0, lA1);
    GLD16(gb0 + k0, lB0);
    GLD16(gb1 + k0, lB1);
    __syncthreads();
    bf16x8 af[4], bf4[4];
#pragma unroll
    for (int i = 0; i < 4; i++)
      af[i] = *(const bf16x8*)&Al[(wm * 64 + i * 16 + r16) * 32 + q * 8];
#pragma unroll
    for (int j = 0; j < 4; j++)
      bf4[j] = *(const bf16x8*)&Bl[(wn * 64 + j * 16 + r16) * 32 + q * 8];
#pragma unroll
    for (int i = 0; i < 4; i++)
#pragma unroll
      for (int j = 0; j < 4; j++)
        acc[i][j] = __builtin_amdgcn_mfma_f32_16x16x32_bf16(af[i], bf4[j], acc[i][j], 0, 0, 0);
  }

#pragma unroll
  for (int i = 0; i < 4; i++) {
    int toks[4]; float ws4[4];
#pragma unroll
    for (int r = 0; r < 4; r++) {
      int pos = m0 + wm * 64 + i * 16 + q * 4 + r;
      if constexpr (ROUTED) {
        bool ok = pos < count;
        toks[r] = ok ? list[e * T_TOK + pos] : -1;
        ws4[r] = ok ? wgt[e * T_TOK + pos] : 0.f;
      } else {
        toks[r] = pos; ws4[r] = 1.f;
      }
    }
#pragma unroll
    for (int j = 0; j < 4; j++) {
      const int col = n0 + wn * 64 + j * 16 + r16;
#pragma unroll
      for (int r = 0; r < 4; r++) {
        if constexpr (ROUTED) {
          if (toks[r] >= 0)
            atomicAdd(&out[(size_t)toks[r] * HDIM + col], ws4[r] * acc[i][j][r]);
        } else {
          size_t idx = (size_t)toks[r] * HDIM + col;
          out[idx] = resid[idx] + acc[i][j][r];
        }
      }
    }
  }
}

extern "C" void kernel_launch(void* const* d_in, const int* in_sizes, int n_in,
                              void* d_out, int out_size, void* d_ws, size_t ws_size,
                              hipStream_t stream) {
  const float* x  = (const float*)d_in[0];
  const float* rw = (const float*)d_in[1];
  const float* sg = (const float*)d_in[2];
  const float* su = (const float*)d_in[3];
  const float* sd = (const float*)d_in[4];
  const float* eg = (const float*)d_in[5];
  const float* eu = (const float*)d_in[6];
  const float* ed = (const float*)d_in[7];
  float* out = (float*)d_out;

  char* ws = (char*)d_ws;
  unsigned short* xb   = (unsigned short*)ws;                     // 4096x1024 bf16
  unsigned short* shid = xb + (size_t)T_TOK * HDIM;               // 4096x1024 bf16
  unsigned short* rhid = shid + (size_t)T_TOK * IDIM;             // 8320x1024 bf16
  int*   cnt  = (int*)(rhid + (size_t)(T_TOK * 2 + 128) * IDIM);
  int*   list = cnt + 16;
  float* wgt  = (float*)(list + EDIM * T_TOK);
  unsigned short* sgT = (unsigned short*)(wgt + EDIM * T_TOK);    // 1024x1024 bf16
  unsigned short* suT = sgT + (size_t)HDIM * IDIM;
  unsigned short* sdT = suT + (size_t)HDIM * IDIM;
  unsigned short* egT = sdT + (size_t)IDIM * HDIM;                // 8x1024x1024
  unsigned short* euT = egT + (size_t)EDIM * HDIM * IDIM;
  unsigned short* edT = euT + (size_t)EDIM * HDIM * IDIM;

  zero_cnt<<<1, 64, 0, stream>>>(cnt);
  convert_x<<<(T_TOK * HDIM) / 1024, 256, 0, stream>>>((const float4*)x, (ushort4*)xb);
  router_topk<<<T_TOK, 64, 0, stream>>>(x, rw, cnt, list, wgt);

  transpose_w<<<dim3(32, 32, 1), 256, 0, stream>>>(sg, sgT);
  transpose_w<<<dim3(32, 32, 1), 256, 0, stream>>>(su, suT);
  transpose_w<<<dim3(32, 32, 1), 256, 0, stream>>>(sd, sdT);
  transpose_w<<<dim3(32, 32, EDIM), 256, 0, stream>>>(eg, egT);
  transpose_w<<<dim3(32, 32, EDIM), 256, 0, stream>>>(eu, euT);
  transpose_w<<<dim3(32, 32, EDIM), 256, 0, stream>>>(ed, edT);

  // shared expert gate/up
  gateup_gemm<false><<<dim3(IDIM / 64, T_TOK / 128, 1), 256, 0, stream>>>(
      xb, sgT, suT, shid, nullptr, nullptr);
  // routed experts gate/up
  gateup_gemm<true><<<dim3(IDIM / 64, T_TOK / 128, EDIM), 256, 0, stream>>>(
      xb, egT, euT, rhid, cnt, list);

  // shared down: out = residual + shared_out
  down_gemm<false><<<dim3(HDIM / 128, T_TOK / 128, 1), 256, 0, stream>>>(
      shid, sdT, out, x, nullptr, nullptr, nullptr);
  // routed down: out += w * expert_out
  down_gemm<true><<<dim3(HDIM / 128, T_TOK / 128, EDIM), 256, 0, stream>>>(
      rhid, edT, out, nullptr, cnt, list, wgt);
}

// Round 3
// 391.060 us; speedup vs baseline: 1.9421x; 1.1930x over previous
//
#include <hip/hip_runtime.h>
#include <hip/hip_bf16.h>

#define T_TOK 4096
#define HDIM 1024
#define IDIM 1024
#define EDIM 8

typedef __attribute__((ext_vector_type(8))) short bf16x8;
typedef __attribute__((ext_vector_type(4))) float f32x4;

static __device__ __forceinline__ unsigned short f2bf(float f) {
  union { float f; unsigned int u; } v; v.f = f;
  unsigned int u = v.u;
  unsigned int r = u + 0x7FFFu + ((u >> 16) & 1u);   // RTNE
  return (unsigned short)(r >> 16);
}

// async global->LDS, 16B per lane; lds dest = wave-uniform base + lane*16
#define GLD16(g, l) __builtin_amdgcn_global_load_lds( \
    (const __attribute__((address_space(1))) void*)(g), \
    (__attribute__((address_space(3))) void*)(l), 16, 0, 0)

// ---------------- x fp32 -> bf16 ----------------
__global__ __launch_bounds__(256) void convert_x(const float4* __restrict__ x4,
                                                 ushort4* __restrict__ xb4) {
  int i = blockIdx.x * 256 + threadIdx.x;
  float4 v = x4[i];
  ushort4 o;
  o.x = f2bf(v.x); o.y = f2bf(v.y); o.z = f2bf(v.z); o.w = f2bf(v.w);
  xb4[i] = o;
}

// ---------------- zero counts ----------------
__global__ void zero_cnt(int* __restrict__ cnt) {
  if (threadIdx.x < 16) cnt[threadIdx.x] = 0;
}

// ---------------- all 27 weight matrices: fp32 [K][N] -> bf16 [N][K] -------
struct SrcPtrs { const float* p[6]; };

__global__ __launch_bounds__(256) void transpose_all(SrcPtrs S,
                                                     unsigned short* __restrict__ dstBase) {
  __shared__ unsigned short t[32][36];
  const int z = blockIdx.z;
  const float* src;
  if (z == 0)       src = S.p[0];
  else if (z == 1)  src = S.p[1];
  else if (z == 2)  src = S.p[2];
  else if (z < 11)  src = S.p[3] + (size_t)(z - 3)  * 1048576;
  else if (z < 19)  src = S.p[4] + (size_t)(z - 11) * 1048576;
  else              src = S.p[5] + (size_t)(z - 19) * 1048576;
  unsigned short* dst = dstBase + (size_t)z * 1048576;

  const int r0 = blockIdx.y * 32;   // K base
  const int c0 = blockIdx.x * 32;   // N base
  const int tid = threadIdx.x;
  const int rr = tid >> 3;          // 0..31
  const int cc = (tid & 7) * 4;     // 0,4,..,28
  const float4 v = *(const float4*)&src[(size_t)(r0 + rr) * 1024 + c0 + cc];
  t[rr][cc + 0] = f2bf(v.x); t[rr][cc + 1] = f2bf(v.y);
  t[rr][cc + 2] = f2bf(v.z); t[rr][cc + 3] = f2bf(v.w);
  __syncthreads();
  const int n = rr;
  const int k4 = cc;
  ushort4 o;
  o.x = t[k4 + 0][n]; o.y = t[k4 + 1][n]; o.z = t[k4 + 2][n]; o.w = t[k4 + 3][n];
  *(ushort4*)&dst[(size_t)(c0 + n) * 1024 + r0 + k4] = o;
}

// ---------------- router: tiled fp32 logits + softmax + top2 ----------------
// 256 blocks x 256 thr; block = 16 tokens. rw staged transposed [h][8] in LDS.
__global__ __launch_bounds__(256) void router2(
    const float* __restrict__ x, const float* __restrict__ rw,
    int* __restrict__ cnt, int* __restrict__ list, float* __restrict__ wgt) {
  __shared__ float rwT[1024 * 8];   // [h][e], 32 KB
  const int tid = threadIdx.x;
  // stage: thread handles h = c*256+tid; 8 coalesced loads, 2 b128 writes
#pragma unroll
  for (int c = 0; c < 4; c++) {
    const int h = c * 256 + tid;
    float v[8];
#pragma unroll
    for (int e = 0; e < EDIM; e++) v[e] = rw[e * 1024 + h];
    *(float4*)&rwT[h * 8]     = make_float4(v[0], v[1], v[2], v[3]);
    *(float4*)&rwT[h * 8 + 4] = make_float4(v[4], v[5], v[6], v[7]);
  }
  __syncthreads();

  const int tt = tid >> 4;          // token within block
  const int pp = tid & 15;          // h-slice
  const int t = blockIdx.x * 16 + tt;
  const float* xr = x + (size_t)t * HDIM;

  float a[EDIM];
#pragma unroll
  for (int e = 0; e < EDIM; e++) a[e] = 0.f;

#pragma unroll 8
  for (int i = 0; i < 64; i++) {
    const int h = pp + 16 * i;
    const float xs = xr[h];
    const float4 r0 = *(const float4*)&rwT[h * 8];
    const float4 r1 = *(const float4*)&rwT[h * 8 + 4];
    a[0] += xs * r0.x; a[1] += xs * r0.y; a[2] += xs * r0.z; a[3] += xs * r0.w;
    a[4] += xs * r1.x; a[5] += xs * r1.y; a[6] += xs * r1.z; a[7] += xs * r1.w;
  }
  // butterfly across the 16-lane slice group
#pragma unroll
  for (int s = 1; s < 16; s <<= 1) {
#pragma unroll
    for (int e = 0; e < EDIM; e++) a[e] += __shfl_xor(a[e], s, 16);
  }
  if (pp == 0) {
    float m = a[0];
#pragma unroll
    for (int e = 1; e < EDIM; e++) m = fmaxf(m, a[e]);
    float p[EDIM]; float s = 0.f;
#pragma unroll
    for (int e = 0; e < EDIM; e++) { p[e] = expf(a[e] - m); s += p[e]; }
    float inv = 1.f / s;
    int e1 = 0; float b1 = p[0];
#pragma unroll
    for (int e = 1; e < EDIM; e++) if (p[e] > b1) { b1 = p[e]; e1 = e; }
    int e2 = -1; float b2 = -1.f;
#pragma unroll
    for (int e = 0; e < EDIM; e++) if (e != e1 && p[e] > b2) { b2 = p[e]; e2 = e; }
    int pos1 = atomicAdd(&cnt[e1], 1);
    list[e1 * T_TOK + pos1] = t; wgt[e1 * T_TOK + pos1] = b1 * inv;
    int pos2 = atomicAdd(&cnt[e2], 1);
    list[e2 * T_TOK + pos2] = t; wgt[e2 * T_TOK + pos2] = b2 * inv;
  }
}

// ---------------- gate/up GEMM: hid = sigmoid(X Wg^T) * (X Wu^T) ------------
// BM=128, BN=64 (per matrix), BK=64, XOR-swizzled chunks. 256 thr = 4 waves.
template <bool GATHER>
__global__ __launch_bounds__(256) void gateup_gemm(
    const unsigned short* __restrict__ xb,
    const unsigned short* __restrict__ WgT_, const unsigned short* __restrict__ WuT_,
    unsigned short* __restrict__ hid,
    const int* __restrict__ cnt, const int* __restrict__ list) {
  __shared__ unsigned short Al[128 * 64];   // 16 KB
  __shared__ unsigned short Bg[64 * 64];    // 8 KB
  __shared__ unsigned short Bu[64 * 64];    // 8 KB

  const int tid = threadIdx.x;
  const int lane = tid & 63;
  const int w = tid >> 6;
  const int wm = w >> 1, wn = w & 1;

  int count, hidbase, e = 0;
  const unsigned short *wg, *wu;
  if constexpr (GATHER) {
    e = blockIdx.z;
    count = cnt[e];
    if ((int)blockIdx.y * 128 >= count) return;
    int off = 0;
#pragma unroll
    for (int i = 0; i < EDIM; i++) off += (i < e) ? cnt[i] : 0;
    hidbase = off;
    wg = WgT_ + (size_t)e * HDIM * IDIM;
    wu = WuT_ + (size_t)e * HDIM * IDIM;
  } else {
    count = T_TOK; hidbase = 0; wg = WgT_; wu = WuT_;
  }
  const int m0 = blockIdx.y * 128;
  const int n0 = blockIdx.x * 64;

  // A staging: 1024 chunks; wave w, issue j: slot = w*256 + j*64 + lane
  const unsigned short* gA[4];
  unsigned short* lA[4];
#pragma unroll
  for (int j = 0; j < 4; j++) {
    const int s = w * 256 + j * 64 + lane;
    const int row = s >> 3;
    const int cg = (s & 7) ^ (row & 7);
    int tok;
    if constexpr (GATHER) {
      int p = m0 + row; if (p >= count) p = count - 1;
      tok = list[e * T_TOK + p];
    } else {
      tok = m0 + row;
    }
    gA[j] = xb + (size_t)tok * HDIM + cg * 8;
    lA[j] = &Al[(w * 256 + j * 64) * 8];
  }
  // B staging: 512 chunks each; wave w, issue j: slot = w*128 + j*64 + lane
  const unsigned short *gG[2], *gU[2];
  unsigned short *lG[2], *lU[2];
#pragma unroll
  for (int j = 0; j < 2; j++) {
    const int s = w * 128 + j * 64 + lane;
    const int row = s >> 3;
    const int cg = (s & 7) ^ (row & 7);
    gG[j] = wg + (size_t)(n0 + row) * HDIM + cg * 8;
    gU[j] = wu + (size_t)(n0 + row) * HDIM + cg * 8;
    lG[j] = &Bg[(w * 128 + j * 64) * 8];
    lU[j] = &Bu[(w * 128 + j * 64) * 8];
  }

  f32x4 accg[4][2], accu[4][2];
  const f32x4 z4 = {0.f, 0.f, 0.f, 0.f};
#pragma unroll
  for (int i = 0; i < 4; i++)
#pragma unroll
    for (int j = 0; j < 2; j++) { accg[i][j] = z4; accu[i][j] = z4; }

  const int q = lane >> 4;
  const int r16 = lane & 15;
  const int rx = r16 & 7;           // row&7 for all fragment rows

  for (int k0 = 0; k0 < HDIM; k0 += 64) {
    __syncthreads();
#pragma unroll
    for (int j = 0; j < 4; j++) GLD16(gA[j] + k0, lA[j]);
#pragma unroll
    for (int j = 0; j < 2; j++) { GLD16(gG[j] + k0, lG[j]); GLD16(gU[j] + k0, lU[j]); }
    __syncthreads();

    bf16x8 af[4][2], bg2[2][2], bu2[2][2];
#pragma unroll
    for (int h = 0; h < 2; h++) {
      const int ch = ((h * 4 + q) ^ rx) * 8;
#pragma unroll
      for (int i = 0; i < 4; i++)
        af[i][h] = *(const bf16x8*)&Al[(wm * 64 + i * 16 + r16) * 64 + ch];
#pragma unroll
      for (int j = 0; j < 2; j++) {
        bg2[j][h] = *(const bf16x8*)&Bg[(wn * 32 + j * 16 + r16) * 64 + ch];
        bu2[j][h] = *(const bf16x8*)&Bu[(wn * 32 + j * 16 + r16) * 64 + ch];
      }
    }
#pragma unroll
    for (int h = 0; h < 2; h++)
#pragma unroll
      for (int i = 0; i < 4; i++)
#pragma unroll
        for (int j = 0; j < 2; j++) {
          accg[i][j] = __builtin_amdgcn_mfma_f32_16x16x32_bf16(af[i][h], bg2[j][h], accg[i][j], 0, 0, 0);
          accu[i][j] = __builtin_amdgcn_mfma_f32_16x16x32_bf16(af[i][h], bu2[j][h], accu[i][j], 0, 0, 0);
        }
  }

#pragma unroll
  for (int i = 0; i < 4; i++) {
#pragma unroll
    for (int j = 0; j < 2; j++) {
      const int col = n0 + wn * 32 + j * 16 + r16;
#pragma unroll
      for (int r = 0; r < 4; r++) {
        int pos = m0 + wm * 64 + i * 16 + q * 4 + r;
        bool ok = GATHER ? (pos < count) : true;
        if (ok) {
          float g = accg[i][j][r], u = accu[i][j][r];
          float h = u / (1.f + __expf(-g));
          hid[(size_t)(hidbase + pos) * IDIM + col] = f2bf(h);
        }
      }
    }
  }
}

// ---------------- down GEMM ----------------
// BM=128, BN=128, BK=64, XOR-swizzled. shared: out = resid + acc.
// routed: atomicAdd(w*acc).
template <bool ROUTED>
__global__ __launch_bounds__(256) void down_gemm(
    const unsigned short* __restrict__ hidin,
    const unsigned short* __restrict__ WdT_,
    float* __restrict__ out, const float* __restrict__ resid,
    const int* __restrict__ cnt, const int* __restrict__ list,
    const float* __restrict__ wgt) {
  __shared__ unsigned short Al[128 * 64];   // 16 KB
  __shared__ unsigned short Bl[128 * 64];   // 16 KB

  const int tid = threadIdx.x;
  const int lane = tid & 63;
  const int w = tid >> 6;
  const int wm = w >> 1, wn = w & 1;

  int count, abase, e = 0;
  const unsigned short* wd;
  if constexpr (ROUTED) {
    e = blockIdx.z;
    count = cnt[e];
    if ((int)blockIdx.y * 128 >= count) return;
    int off = 0;
#pragma unroll
    for (int i = 0; i < EDIM; i++) off += (i < e) ? cnt[i] : 0;
    abase = off;
    wd = WdT_ + (size_t)e * IDIM * HDIM;
  } else {
    count = T_TOK; abase = 0; wd = WdT_;
  }
  const int m0 = blockIdx.y * 128;
  const int n0 = blockIdx.x * 128;

  const unsigned short *gA[4], *gB[4];
  unsigned short *lA[4], *lB[4];
#pragma unroll
  for (int j = 0; j < 4; j++) {
    const int s = w * 256 + j * 64 + lane;
    const int row = s >> 3;
    const int cg = (s & 7) ^ (row & 7);
    gA[j] = hidin + (size_t)(abase + m0 + row) * IDIM + cg * 8;
    gB[j] = wd + (size_t)(n0 + row) * IDIM + cg * 8;
    lA[j] = &Al[(w * 256 + j * 64) * 8];
    lB[j] = &Bl[(w * 256 + j * 64) * 8];
  }

  f32x4 acc[4][4];
  const f32x4 z4 = {0.f, 0.f, 0.f, 0.f};
#pragma unroll
  for (int i = 0; i < 4; i++)
#pragma unroll
    for (int j = 0; j < 4; j++) acc[i][j] = z4;

  const int q = lane >> 4;
  const int r16 = lane & 15;
  const int rx = r16 & 7;

  for (int k0 = 0; k0 < IDIM; k0 += 64) {
    __syncthreads();
#pragma unroll
    for (int j = 0; j < 4; j++) GLD16(gA[j] + k0, lA[j]);
#pragma unroll
    for (int j = 0; j < 4; j++) GLD16(gB[j] + k0, lB[j]);
    __syncthreads();

    bf16x8 af[4][2], bf4[4][2];
#pragma unroll
    for (int h = 0; h < 2; h++) {
      const int ch = ((h * 4 + q) ^ rx) * 8;
#pragma unroll
      for (int i = 0; i < 4; i++)
        af[i][h] = *(const bf16x8*)&Al[(wm * 64 + i * 16 + r16) * 64 + ch];
#pragma unroll
      for (int j = 0; j < 4; j++)
        bf4[j][h] = *(const bf16x8*)&Bl[(wn * 64 + j * 16 + r16) * 64 + ch];
    }
#pragma unroll
    for (int h = 0; h < 2; h++)
#pragma unroll
      for (int i = 0; i < 4; i++)
#pragma unroll
        for (int j = 0; j < 4; j++)
          acc[i][j] = __builtin_amdgcn_mfma_f32_16x16x32_bf16(af[i][h], bf4[j][h], acc[i][j], 0, 0, 0);
  }

#pragma unroll
  for (int i = 0; i < 4; i++) {
    int toks[4]; float ws4[4];
#pragma unroll
    for (int r = 0; r < 4; r++) {
      int pos = m0 + wm * 64 + i * 16 + q * 4 + r;
      if constexpr (ROUTED) {
        bool ok = pos < count;
        toks[r] = ok ? list[e * T_TOK + pos] : -1;
        ws4[r] = ok ? wgt[e * T_TOK + pos] : 0.f;
      } else {
        toks[r] = pos; ws4[r] = 1.f;
      }
    }
#pragma unroll
    for (int j = 0; j < 4; j++) {
      const int col = n0 + wn * 64 + j * 16 + r16;
#pragma unroll
      for (int r = 0; r < 4; r++) {
        if constexpr (ROUTED) {
          if (toks[r] >= 0)
            atomicAdd(&out[(size_t)toks[r] * HDIM + col], ws4[r] * acc[i][j][r]);
        } else {
          size_t idx = (size_t)toks[r] * HDIM + col;
          out[idx] = resid[idx] + acc[i][j][r];
        }
      }
    }
  }
}

extern "C" void kernel_launch(void* const* d_in, const int* in_sizes, int n_in,
                              void* d_out, int out_size, void* d_ws, size_t ws_size,
                              hipStream_t stream) {
  const float* x  = (const float*)d_in[0];
  const float* rw = (const float*)d_in[1];
  const float* sg = (const float*)d_in[2];
  const float* su = (const float*)d_in[3];
  const float* sd = (const float*)d_in[4];
  const float* eg = (const float*)d_in[5];
  const float* eu = (const float*)d_in[6];
  const float* ed = (const float*)d_in[7];
  float* out = (float*)d_out;

  char* ws = (char*)d_ws;
  unsigned short* xb   = (unsigned short*)ws;                     // 4096x1024 bf16
  unsigned short* shid = xb + (size_t)T_TOK * HDIM;               // 4096x1024 bf16
  unsigned short* rhid = shid + (size_t)T_TOK * IDIM;             // 8320x1024 bf16
  int*   cnt  = (int*)(rhid + (size_t)(T_TOK * 2 + 128) * IDIM);
  int*   list = cnt + 16;
  float* wgt  = (float*)(list + EDIM * T_TOK);
  unsigned short* wT = (unsigned short*)(wgt + EDIM * T_TOK);     // 27 x 1M bf16
  unsigned short* sgT = wT;
  unsigned short* suT = sgT + (size_t)HDIM * IDIM;
  unsigned short* sdT = suT + (size_t)HDIM * IDIM;
  unsigned short* egT = sdT + (size_t)IDIM * HDIM;
  unsigned short* euT = egT + (size_t)EDIM * HDIM * IDIM;
  unsigned short* edT = euT + (size_t)EDIM * HDIM * IDIM;

  zero_cnt<<<1, 64, 0, stream>>>(cnt);
  convert_x<<<(T_TOK * HDIM) / 1024, 256, 0, stream>>>((const float4*)x, (ushort4*)xb);
  router2<<<T_TOK / 16, 256, 0, stream>>>(x, rw, cnt, list, wgt);

  SrcPtrs S; S.p[0] = sg; S.p[1] = su; S.p[2] = sd; S.p[3] = eg; S.p[4] = eu; S.p[5] = ed;
  transpose_all<<<dim3(32, 32, 27), 256, 0, stream>>>(S, wT);

  // shared expert gate/up
  gateup_gemm<false><<<dim3(IDIM / 64, T_TOK / 128, 1), 256, 0, stream>>>(
      xb, sgT, suT, shid, nullptr, nullptr);
  // routed experts gate/up
  gateup_gemm<true><<<dim3(IDIM / 64, T_TOK / 128, EDIM), 256, 0, stream>>>(
      xb, egT, euT, rhid, cnt, list);

  // shared down: out = residual + shared_out
  down_gemm<false><<<dim3(HDIM / 128, T_TOK / 128, 1), 256, 0, stream>>>(
      shid, sdT, out, x, nullptr, nullptr, nullptr);
  // routed down: out += w * expert_out
  down_gemm<true><<<dim3(HDIM / 128, T_TOK / 128, EDIM), 256, 0, stream>>>(
      rhid, edT, out, nullptr, cnt, list, wgt);
}

// Round 4
// 386.789 us; speedup vs baseline: 1.9635x; 1.0110x over previous
//
#include <hip/hip_runtime.h>
#include <hip/hip_bf16.h>

#define T_TOK 4096
#define HDIM 1024
#define IDIM 1024
#define EDIM 8
#define HID_SHARED_BASE 8320   // routed hid rows [0,8320) incl. slack; shared at [8320,12416)

typedef __attribute__((ext_vector_type(8))) short bf16x8;
typedef __attribute__((ext_vector_type(4))) float f32x4;

static __device__ __forceinline__ unsigned short f2bf(float f) {
  union { float f; unsigned int u; } v; v.f = f;
  unsigned int u = v.u;
  unsigned int r = u + 0x7FFFu + ((u >> 16) & 1u);   // RTNE
  return (unsigned short)(r >> 16);
}

// async global->LDS, 16B per lane; lds dest = wave-uniform base + lane*16
#define GLD16(g, l) __builtin_amdgcn_global_load_lds( \
    (const __attribute__((address_space(1))) void*)(g), \
    (__attribute__((address_space(3))) void*)(l), 16, 0, 0)

// ---------------- x fp32 -> bf16, and out pre-init with residual ------------
__global__ __launch_bounds__(256) void convert_x(const float4* __restrict__ x4,
                                                 ushort4* __restrict__ xb4,
                                                 float4* __restrict__ out4) {
  int i = blockIdx.x * 256 + threadIdx.x;
  float4 v = x4[i];
  out4[i] = v;                       // residual
  ushort4 o;
  o.x = f2bf(v.x); o.y = f2bf(v.y); o.z = f2bf(v.z); o.w = f2bf(v.w);
  xb4[i] = o;
}

// ---------------- zero counts ----------------
__global__ void zero_cnt(int* __restrict__ cnt) {
  if (threadIdx.x < 16) cnt[threadIdx.x] = 0;
}

// ---------------- all 27 weight matrices: fp32 [K][N] -> bf16 [N][K] -------
// dst layout: gateT[9] | upT[9] | downT[9], expert slot 8 = shared expert.
struct SrcPtrs { const float* p[6]; };

__global__ __launch_bounds__(256) void transpose_all(SrcPtrs S,
                                                     unsigned short* __restrict__ dstBase) {
  __shared__ unsigned short t[32][36];
  const int z = blockIdx.z;
  const float* src; int dz;
  if (z == 0)      { src = S.p[0];                              dz = 8;  }
  else if (z == 1) { src = S.p[1];                              dz = 17; }
  else if (z == 2) { src = S.p[2];                              dz = 26; }
  else if (z < 11) { src = S.p[3] + (size_t)(z - 3)  * 1048576; dz = z - 3; }
  else if (z < 19) { src = S.p[4] + (size_t)(z - 11) * 1048576; dz = 9 + (z - 11); }
  else             { src = S.p[5] + (size_t)(z - 19) * 1048576; dz = 18 + (z - 19); }
  unsigned short* dst = dstBase + (size_t)dz * 1048576;

  const int r0 = blockIdx.y * 32;
  const int c0 = blockIdx.x * 32;
  const int tid = threadIdx.x;
  const int rr = tid >> 3;
  const int cc = (tid & 7) * 4;
  const float4 v = *(const float4*)&src[(size_t)(r0 + rr) * 1024 + c0 + cc];
  t[rr][cc + 0] = f2bf(v.x); t[rr][cc + 1] = f2bf(v.y);
  t[rr][cc + 2] = f2bf(v.z); t[rr][cc + 3] = f2bf(v.w);
  __syncthreads();
  ushort4 o;
  o.x = t[cc + 0][rr]; o.y = t[cc + 1][rr]; o.z = t[cc + 2][rr]; o.w = t[cc + 3][rr];
  *(ushort4*)&dst[(size_t)(c0 + rr) * 1024 + r0 + cc] = o;
}

// ---------------- router: tiled fp32 logits + softmax + top2 ----------------
__global__ __launch_bounds__(256) void router2(
    const float* __restrict__ x, const float* __restrict__ rw,
    int* __restrict__ cnt, int* __restrict__ list, float* __restrict__ wgt) {
  __shared__ float rwT[1024 * 8];
  const int tid = threadIdx.x;
#pragma unroll
  for (int c = 0; c < 4; c++) {
    const int h = c * 256 + tid;
    float v[8];
#pragma unroll
    for (int e = 0; e < EDIM; e++) v[e] = rw[e * 1024 + h];
    *(float4*)&rwT[h * 8]     = make_float4(v[0], v[1], v[2], v[3]);
    *(float4*)&rwT[h * 8 + 4] = make_float4(v[4], v[5], v[6], v[7]);
  }
  __syncthreads();

  const int tt = tid >> 4;
  const int pp = tid & 15;
  const int t = blockIdx.x * 16 + tt;
  const float* xr = x + (size_t)t * HDIM;

  float a[EDIM];
#pragma unroll
  for (int e = 0; e < EDIM; e++) a[e] = 0.f;

#pragma unroll 8
  for (int i = 0; i < 64; i++) {
    const int h = pp + 16 * i;
    const float xs = xr[h];
    const float4 r0 = *(const float4*)&rwT[h * 8];
    const float4 r1 = *(const float4*)&rwT[h * 8 + 4];
    a[0] += xs * r0.x; a[1] += xs * r0.y; a[2] += xs * r0.z; a[3] += xs * r0.w;
    a[4] += xs * r1.x; a[5] += xs * r1.y; a[6] += xs * r1.z; a[7] += xs * r1.w;
  }
#pragma unroll
  for (int s = 1; s < 16; s <<= 1) {
#pragma unroll
    for (int e = 0; e < EDIM; e++) a[e] += __shfl_xor(a[e], s, 16);
  }
  if (pp == 0) {
    float m = a[0];
#pragma unroll
    for (int e = 1; e < EDIM; e++) m = fmaxf(m, a[e]);
    float p[EDIM]; float s = 0.f;
#pragma unroll
    for (int e = 0; e < EDIM; e++) { p[e] = expf(a[e] - m); s += p[e]; }
    float inv = 1.f / s;
    int e1 = 0; float b1 = p[0];
#pragma unroll
    for (int e = 1; e < EDIM; e++) if (p[e] > b1) { b1 = p[e]; e1 = e; }
    int e2 = -1; float b2 = -1.f;
#pragma unroll
    for (int e = 0; e < EDIM; e++) if (e != e1 && p[e] > b2) { b2 = p[e]; e2 = e; }
    int pos1 = atomicAdd(&cnt[e1], 1);
    list[e1 * T_TOK + pos1] = t; wgt[e1 * T_TOK + pos1] = b1 * inv;
    int pos2 = atomicAdd(&cnt[e2], 1);
    list[e2 * T_TOK + pos2] = t; wgt[e2 * T_TOK + pos2] = b2 * inv;
  }
}

// ---------------- fused gate/up GEMM (z=0..7 routed, z=8 shared) ------------
// BM=128, BN=64, BK=32, double-buffered LDS, 1 barrier per K-step.
__global__ __launch_bounds__(256) void gateup_f(
    const unsigned short* __restrict__ xb,
    const unsigned short* __restrict__ gateT,
    const unsigned short* __restrict__ upT,
    unsigned short* __restrict__ hid,
    const int* __restrict__ cnt, const int* __restrict__ list) {
  __shared__ unsigned short Al[2][128 * 32];  // 16 KB
  __shared__ unsigned short Bg[2][64 * 32];   // 8 KB
  __shared__ unsigned short Bu[2][64 * 32];   // 8 KB

  const int tid = threadIdx.x;
  const int lane = tid & 63;
  const int w = tid >> 6;
  const int wm = w >> 1, wn = w & 1;
  const int z = blockIdx.z;
  const int m0 = blockIdx.y * 128;
  const int n0 = blockIdx.x * 64;

  int count, hidbase;
  if (z < EDIM) {
    count = cnt[z];
    if (m0 >= count) return;
    int off = 0;
#pragma unroll
    for (int i = 0; i < EDIM; i++) off += (i < z) ? cnt[i] : 0;
    hidbase = off;
  } else {
    count = T_TOK;
    hidbase = HID_SHARED_BASE;
  }
  const unsigned short* wg = gateT + (size_t)z * HDIM * IDIM;
  const unsigned short* wu = upT   + (size_t)z * HDIM * IDIM;

  // A staging: 512 chunks of 16B; wave w, issue j: slot = w*128 + j*64 + lane
  const unsigned short* gA[2];
#pragma unroll
  for (int j = 0; j < 2; j++) {
    const int s = w * 128 + j * 64 + lane;
    const int row = s >> 2;
    const int g = (s & 3) ^ ((row + (row >> 2)) & 3);
    int tok;
    if (z < EDIM) {
      int p = m0 + row; if (p >= count) p = count - 1;
      tok = list[z * T_TOK + p];
    } else tok = m0 + row;
    gA[j] = xb + (size_t)tok * HDIM + g * 8;
  }
  // B staging: 256 chunks each; slot = w*64 + lane
  const int sB = w * 64 + lane;
  const int rowB = sB >> 2;
  const int gB = (sB & 3) ^ ((rowB + (rowB >> 2)) & 3);
  const unsigned short* gGp = wg + (size_t)(n0 + rowB) * HDIM + gB * 8;
  const unsigned short* gUp = wu + (size_t)(n0 + rowB) * HDIM + gB * 8;

  f32x4 accg[4][2], accu[4][2];
  const f32x4 z4 = {0.f, 0.f, 0.f, 0.f};
#pragma unroll
  for (int i = 0; i < 4; i++)
#pragma unroll
    for (int j = 0; j < 2; j++) { accg[i][j] = z4; accu[i][j] = z4; }

  const int q = lane >> 4;
  const int r16 = lane & 15;
  const int ch = (q ^ ((r16 + (r16 >> 2)) & 3)) * 8;

  auto stage = [&](int k0, int b) {
    GLD16(gA[0] + k0, &Al[b][(w * 128) * 8]);
    GLD16(gA[1] + k0, &Al[b][(w * 128 + 64) * 8]);
    GLD16(gGp + k0, &Bg[b][(w * 64) * 8]);
    GLD16(gUp + k0, &Bu[b][(w * 64) * 8]);
  };
  auto compute = [&](int b) {
    bf16x8 af[4], bg2[2], bu2[2];
#pragma unroll
    for (int i = 0; i < 4; i++)
      af[i] = *(const bf16x8*)&Al[b][(wm * 64 + i * 16 + r16) * 32 + ch];
#pragma unroll
    for (int j = 0; j < 2; j++) {
      bg2[j] = *(const bf16x8*)&Bg[b][(wn * 32 + j * 16 + r16) * 32 + ch];
      bu2[j] = *(const bf16x8*)&Bu[b][(wn * 32 + j * 16 + r16) * 32 + ch];
    }
#pragma unroll
    for (int i = 0; i < 4; i++)
#pragma unroll
      for (int j = 0; j < 2; j++) {
        accg[i][j] = __builtin_amdgcn_mfma_f32_16x16x32_bf16(af[i], bg2[j], accg[i][j], 0, 0, 0);
        accu[i][j] = __builtin_amdgcn_mfma_f32_16x16x32_bf16(af[i], bu2[j], accu[i][j], 0, 0, 0);
      }
  };

  stage(0, 0);
#pragma unroll 1
  for (int p = 0; p < 16; p++) {
    __syncthreads();
    stage((2 * p + 1) * 32, 1);      // prefetch overlaps compute(0)
    compute(0);
    __syncthreads();
    if (p < 15) stage((2 * p + 2) * 32, 0);
    compute(1);
  }

#pragma unroll
  for (int i = 0; i < 4; i++) {
#pragma unroll
    for (int j = 0; j < 2; j++) {
      const int col = n0 + wn * 32 + j * 16 + r16;
#pragma unroll
      for (int r = 0; r < 4; r++) {
        int pos = m0 + wm * 64 + i * 16 + q * 4 + r;
        if (pos < count) {
          float g = accg[i][j][r], u = accu[i][j][r];
          float h = u / (1.f + __expf(-g));
          hid[(size_t)(hidbase + pos) * IDIM + col] = f2bf(h);
        }
      }
    }
  }
}

// ---------------- fused down GEMM (z=0..7 routed, z=8 shared) ---------------
// BM=128, BN=128, BK=32, double-buffered, 1 barrier per K-step. All atomicAdd
// (out pre-initialized with residual by convert_x).
__global__ __launch_bounds__(256) void down_f(
    const unsigned short* __restrict__ hid,
    const unsigned short* __restrict__ downT,
    float* __restrict__ out,
    const int* __restrict__ cnt, const int* __restrict__ list,
    const float* __restrict__ wgt) {
  __shared__ unsigned short Al[2][128 * 32];  // 16 KB
  __shared__ unsigned short Bl[2][128 * 32];  // 16 KB

  const int tid = threadIdx.x;
  const int lane = tid & 63;
  const int w = tid >> 6;
  const int wm = w >> 1, wn = w & 1;
  const int z = blockIdx.z;
  const int m0 = blockIdx.y * 128;
  const int n0 = blockIdx.x * 128;

  int count, abase;
  if (z < EDIM) {
    count = cnt[z];
    if (m0 >= count) return;
    int off = 0;
#pragma unroll
    for (int i = 0; i < EDIM; i++) off += (i < z) ? cnt[i] : 0;
    abase = off;
  } else {
    count = T_TOK;
    abase = HID_SHARED_BASE;
  }
  const unsigned short* wd = downT + (size_t)z * IDIM * HDIM;

  const unsigned short *gA[2], *gBp[2];
#pragma unroll
  for (int j = 0; j < 2; j++) {
    const int s = w * 128 + j * 64 + lane;
    const int row = s >> 2;
    const int g = (s & 3) ^ ((row + (row >> 2)) & 3);
    gA[j]  = hid + (size_t)(abase + m0 + row) * IDIM + g * 8;
    gBp[j] = wd + (size_t)(n0 + row) * IDIM + g * 8;
  }

  f32x4 acc[4][4];
  const f32x4 z4 = {0.f, 0.f, 0.f, 0.f};
#pragma unroll
  for (int i = 0; i < 4; i++)
#pragma unroll
    for (int j = 0; j < 4; j++) acc[i][j] = z4;

  const int q = lane >> 4;
  const int r16 = lane & 15;
  const int ch = (q ^ ((r16 + (r16 >> 2)) & 3)) * 8;

  auto stage = [&](int k0, int b) {
    GLD16(gA[0] + k0,  &Al[b][(w * 128) * 8]);
    GLD16(gA[1] + k0,  &Al[b][(w * 128 + 64) * 8]);
    GLD16(gBp[0] + k0, &Bl[b][(w * 128) * 8]);
    GLD16(gBp[1] + k0, &Bl[b][(w * 128 + 64) * 8]);
  };
  auto compute = [&](int b) {
    bf16x8 af[4], bf4[4];
#pragma unroll
    for (int i = 0; i < 4; i++)
      af[i] = *(const bf16x8*)&Al[b][(wm * 64 + i * 16 + r16) * 32 + ch];
#pragma unroll
    for (int j = 0; j < 4; j++)
      bf4[j] = *(const bf16x8*)&Bl[b][(wn * 64 + j * 16 + r16) * 32 + ch];
#pragma unroll
    for (int i = 0; i < 4; i++)
#pragma unroll
      for (int j = 0; j < 4; j++)
        acc[i][j] = __builtin_amdgcn_mfma_f32_16x16x32_bf16(af[i], bf4[j], acc[i][j], 0, 0, 0);
  };

  stage(0, 0);
#pragma unroll 1
  for (int p = 0; p < 16; p++) {
    __syncthreads();
    stage((2 * p + 1) * 32, 1);
    compute(0);
    __syncthreads();
    if (p < 15) stage((2 * p + 2) * 32, 0);
    compute(1);
  }

#pragma unroll
  for (int i = 0; i < 4; i++) {
    int toks[4]; float ws4[4];
#pragma unroll
    for (int r = 0; r < 4; r++) {
      int pos = m0 + wm * 64 + i * 16 + q * 4 + r;
      if (z < EDIM) {
        bool ok = pos < count;
        toks[r] = ok ? list[z * T_TOK + pos] : -1;
        ws4[r] = ok ? wgt[z * T_TOK + pos] : 0.f;
      } else {
        toks[r] = pos; ws4[r] = 1.f;
      }
    }
#pragma unroll
    for (int j = 0; j < 4; j++) {
      const int col = n0 + wn * 64 + j * 16 + r16;
#pragma unroll
      for (int r = 0; r < 4; r++) {
        if (toks[r] >= 0)
          atomicAdd(&out[(size_t)toks[r] * HDIM + col], ws4[r] * acc[i][j][r]);
      }
    }
  }
}

extern "C" void kernel_launch(void* const* d_in, const int* in_sizes, int n_in,
                              void* d_out, int out_size, void* d_ws, size_t ws_size,
                              hipStream_t stream) {
  const float* x  = (const float*)d_in[0];
  const float* rw = (const float*)d_in[1];
  const float* sg = (const float*)d_in[2];
  const float* su = (const float*)d_in[3];
  const float* sd = (const float*)d_in[4];
  const float* eg = (const float*)d_in[5];
  const float* eu = (const float*)d_in[6];
  const float* ed = (const float*)d_in[7];
  float* out = (float*)d_out;

  char* ws = (char*)d_ws;
  unsigned short* xb  = (unsigned short*)ws;                          // 4096x1024 bf16
  unsigned short* hid = xb + (size_t)T_TOK * HDIM;                    // 12416x1024 bf16
  int*   cnt  = (int*)(hid + (size_t)(HID_SHARED_BASE + T_TOK) * IDIM);
  int*   list = cnt + 16;
  float* wgt  = (float*)(list + EDIM * T_TOK);
  unsigned short* wT    = (unsigned short*)(wgt + EDIM * T_TOK);      // 27 x 1M bf16
  unsigned short* gateT = wT;
  unsigned short* upT   = wT + (size_t)9 * 1048576;
  unsigned short* downT = wT + (size_t)18 * 1048576;

  zero_cnt<<<1, 64, 0, stream>>>(cnt);
  convert_x<<<(T_TOK * HDIM) / 1024, 256, 0, stream>>>(
      (const float4*)x, (ushort4*)xb, (float4*)out);
  router2<<<T_TOK / 16, 256, 0, stream>>>(x, rw, cnt, list, wgt);

  SrcPtrs S; S.p[0] = sg; S.p[1] = su; S.p[2] = sd; S.p[3] = eg; S.p[4] = eu; S.p[5] = ed;
  transpose_all<<<dim3(32, 32, 27), 256, 0, stream>>>(S, wT);

  gateup_f<<<dim3(IDIM / 64, 32, 9), 256, 0, stream>>>(xb, gateT, upT, hid, cnt, list);
  down_f<<<dim3(HDIM / 128, 32, 9), 256, 0, stream>>>(hid, downT, out, cnt, list, wgt);
}

// Round 5
// 378.532 us; speedup vs baseline: 2.0063x; 1.0218x over previous
//
#include <hip/hip_runtime.h>
#include <hip/hip_bf16.h>

#define T_TOK 4096
#define HDIM 1024
#define IDIM 1024
#define EDIM 8
#define HID_SHARED_BASE 8320   // routed hid rows [0,8320); shared at [8320,12416)

typedef __attribute__((ext_vector_type(8))) short bf16x8;
typedef __attribute__((ext_vector_type(4))) float f32x4;

static __device__ __forceinline__ unsigned short f2bf(float f) {
  union { float f; unsigned int u; } v; v.f = f;
  unsigned int u = v.u;
  unsigned int r = u + 0x7FFFu + ((u >> 16) & 1u);   // RTNE
  return (unsigned short)(r >> 16);
}

// async global->LDS, 16B per lane; lds dest = wave-uniform base + lane*16
#define GLD16(g, l) __builtin_amdgcn_global_load_lds( \
    (const __attribute__((address_space(1))) void*)(g), \
    (__attribute__((address_space(3))) void*)(l), 16, 0, 0)

// ---------------- x fp32 -> bf16, and out pre-init with residual ------------
__global__ __launch_bounds__(256) void convert_x(const float4* __restrict__ x4,
                                                 ushort4* __restrict__ xb4,
                                                 float4* __restrict__ out4) {
  int i = blockIdx.x * 256 + threadIdx.x;
  float4 v = x4[i];
  out4[i] = v;                       // residual
  ushort4 o;
  o.x = f2bf(v.x); o.y = f2bf(v.y); o.z = f2bf(v.z); o.w = f2bf(v.w);
  xb4[i] = o;
}

// ---------------- zero counts ----------------
__global__ void zero_cnt(int* __restrict__ cnt) {
  if (threadIdx.x < 16) cnt[threadIdx.x] = 0;
}

// ---------------- all 27 weight matrices: fp32 [K][N] -> bf16 [N][K] -------
// 64x64 tiles; coalesced float4 reads + 16B ushort8 writes; swizzled LDS.
// dst layout: gateT[9] | upT[9] | downT[9], expert slot 8 = shared expert.
struct SrcPtrs { const float* p[6]; };

__global__ __launch_bounds__(256) void transpose_all(SrcPtrs S,
                                                     unsigned short* __restrict__ dstBase) {
  __shared__ unsigned short t[64][72];   // 18 KB, row stride 144B (16B aligned)
  const int z = blockIdx.z;
  const float* src; int dz;
  if (z == 0)      { src = S.p[0];                              dz = 8;  }
  else if (z == 1) { src = S.p[1];                              dz = 17; }
  else if (z == 2) { src = S.p[2];                              dz = 26; }
  else if (z < 11) { src = S.p[3] + (size_t)(z - 3)  * 1048576; dz = z - 3; }
  else if (z < 19) { src = S.p[4] + (size_t)(z - 11) * 1048576; dz = 9 + (z - 11); }
  else             { src = S.p[5] + (size_t)(z - 19) * 1048576; dz = 18 + (z - 19); }
  unsigned short* dst = dstBase + (size_t)dz * 1048576;

  const int r0 = blockIdx.y * 64;   // K base
  const int c0 = blockIdx.x * 64;   // N base
  const int tid = threadIdx.x;

  // read: 4 phases; thread -> (row rr+16*ph, cols c4..c4+3)
  const int rr = tid >> 4;          // 0..15
  const int c4 = (tid & 15) * 4;    // 0..60
#pragma unroll
  for (int ph = 0; ph < 4; ph++) {
    const int r = rr + ph * 16;
    const float4 v = *(const float4*)&src[(size_t)(r0 + r) * 1024 + c0 + c4];
    const int cs = c4 ^ (4 * (r >> 3));       // swizzle bits 2-4 of col
    t[r][cs + 0] = f2bf(v.x); t[r][cs + 1] = f2bf(v.y);
    t[r][cs + 2] = f2bf(v.z); t[r][cs + 3] = f2bf(v.w);
  }
  __syncthreads();

  // write: 2 phases; thread -> (n-row, 8 k's) -> 16B store
  const int n = tid >> 3;           // 0..31
  const int k8 = (tid & 7) * 8;     // 0..56
  const int m = k8 >> 3;            // (k8+j)>>3 == m for j<8
#pragma unroll
  for (int ph = 0; ph < 2; ph++) {
    const int nn = n + ph * 32;
    const int ns = nn ^ (4 * m);
    unsigned short v[8];
#pragma unroll
    for (int j = 0; j < 8; j++) v[j] = t[k8 + j][ns];
    *(bf16x8*)&dst[(size_t)(c0 + nn) * 1024 + r0 + k8] = *(const bf16x8*)v;
  }
}

// ---------------- router: tiled fp32 logits + softmax + top2 ----------------
__global__ __launch_bounds__(256) void router2(
    const float* __restrict__ x, const float* __restrict__ rw,
    int* __restrict__ cnt, int* __restrict__ list, float* __restrict__ wgt) {
  __shared__ float rwT[1024 * 8];
  const int tid = threadIdx.x;
#pragma unroll
  for (int c = 0; c < 4; c++) {
    const int h = c * 256 + tid;
    float v[8];
#pragma unroll
    for (int e = 0; e < EDIM; e++) v[e] = rw[e * 1024 + h];
    *(float4*)&rwT[h * 8]     = make_float4(v[0], v[1], v[2], v[3]);
    *(float4*)&rwT[h * 8 + 4] = make_float4(v[4], v[5], v[6], v[7]);
  }
  __syncthreads();

  const int tt = tid >> 4;
  const int pp = tid & 15;
  const int t = blockIdx.x * 16 + tt;
  const float* xr = x + (size_t)t * HDIM;

  float a[EDIM];
#pragma unroll
  for (int e = 0; e < EDIM; e++) a[e] = 0.f;

#pragma unroll 8
  for (int i = 0; i < 64; i++) {
    const int h = pp + 16 * i;
    const float xs = xr[h];
    const float4 r0 = *(const float4*)&rwT[h * 8];
    const float4 r1 = *(const float4*)&rwT[h * 8 + 4];
    a[0] += xs * r0.x; a[1] += xs * r0.y; a[2] += xs * r0.z; a[3] += xs * r0.w;
    a[4] += xs * r1.x; a[5] += xs * r1.y; a[6] += xs * r1.z; a[7] += xs * r1.w;
  }
#pragma unroll
  for (int s = 1; s < 16; s <<= 1) {
#pragma unroll
    for (int e = 0; e < EDIM; e++) a[e] += __shfl_xor(a[e], s, 16);
  }
  if (pp == 0) {
    float m = a[0];
#pragma unroll
    for (int e = 1; e < EDIM; e++) m = fmaxf(m, a[e]);
    float p[EDIM]; float s = 0.f;
#pragma unroll
    for (int e = 0; e < EDIM; e++) { p[e] = expf(a[e] - m); s += p[e]; }
    float inv = 1.f / s;
    int e1 = 0; float b1 = p[0];
#pragma unroll
    for (int e = 1; e < EDIM; e++) if (p[e] > b1) { b1 = p[e]; e1 = e; }
    int e2 = -1; float b2 = -1.f;
#pragma unroll
    for (int e = 0; e < EDIM; e++) if (e != e1 && p[e] > b2) { b2 = p[e]; e2 = e; }
    int pos1 = atomicAdd(&cnt[e1], 1);
    list[e1 * T_TOK + pos1] = t; wgt[e1 * T_TOK + pos1] = b1 * inv;
    int pos2 = atomicAdd(&cnt[e2], 1);
    list[e2 * T_TOK + pos2] = t; wgt[e2 * T_TOK + pos2] = b2 * inv;
  }
}

// ---------------- fused gate/up GEMM (z=0..7 routed, z=8 shared) ------------
// BM=128, BN=64, BK=32. 3-stage LDS pipeline, raw s_barrier + manual vmcnt —
// loads stay in flight across the barrier (no vmcnt(0) drain).
__global__ __launch_bounds__(256) void gateup_f(
    const unsigned short* __restrict__ xb,
    const unsigned short* __restrict__ gateT,
    const unsigned short* __restrict__ upT,
    unsigned short* __restrict__ hid,
    const int* __restrict__ cnt, const int* __restrict__ list) {
  __shared__ unsigned short Al[3][128 * 32];  // 24 KB
  __shared__ unsigned short Bg[3][64 * 32];   // 12 KB
  __shared__ unsigned short Bu[3][64 * 32];   // 12 KB

  const int tid = threadIdx.x;
  const int lane = tid & 63;
  const int w = tid >> 6;
  const int wm = w >> 1, wn = w & 1;
  const int z = blockIdx.z;
  const int m0 = blockIdx.y * 128;
  const int n0 = blockIdx.x * 64;

  int count, hidbase;
  if (z < EDIM) {
    count = cnt[z];
    if (m0 >= count) return;
    int off = 0;
#pragma unroll
    for (int i = 0; i < EDIM; i++) off += (i < z) ? cnt[i] : 0;
    hidbase = off;
  } else {
    count = T_TOK;
    hidbase = HID_SHARED_BASE;
  }
  const unsigned short* wg = gateT + (size_t)z * HDIM * IDIM;
  const unsigned short* wu = upT   + (size_t)z * HDIM * IDIM;

  // A staging: 512 chunks of 16B; wave w, issue j: slot = w*128 + j*64 + lane
  const unsigned short* gA[2];
#pragma unroll
  for (int j = 0; j < 2; j++) {
    const int s = w * 128 + j * 64 + lane;
    const int row = s >> 2;
    const int g = (s & 3) ^ ((row + (row >> 2)) & 3);
    int tok;
    if (z < EDIM) {
      int p = m0 + row; if (p >= count) p = count - 1;
      tok = list[z * T_TOK + p];
    } else tok = m0 + row;
    gA[j] = xb + (size_t)tok * HDIM + g * 8;
  }
  // B staging: 256 chunks each; slot = w*64 + lane
  const int sB = w * 64 + lane;
  const int rowB = sB >> 2;
  const int gB = (sB & 3) ^ ((rowB + (rowB >> 2)) & 3);
  const unsigned short* gGp = wg + (size_t)(n0 + rowB) * HDIM + gB * 8;
  const unsigned short* gUp = wu + (size_t)(n0 + rowB) * HDIM + gB * 8;

  f32x4 accg[4][2], accu[4][2];
  const f32x4 z4 = {0.f, 0.f, 0.f, 0.f};
#pragma unroll
  for (int i = 0; i < 4; i++)
#pragma unroll
    for (int j = 0; j < 2; j++) { accg[i][j] = z4; accu[i][j] = z4; }

  const int q = lane >> 4;
  const int r16 = lane & 15;
  const int ch = (q ^ ((r16 + (r16 >> 2)) & 3)) * 8;

  auto stage = [&](int k0, int b) {
    GLD16(gA[0] + k0, &Al[b][(w * 128) * 8]);
    GLD16(gA[1] + k0, &Al[b][(w * 128 + 64) * 8]);
    GLD16(gGp + k0, &Bg[b][(w * 64) * 8]);
    GLD16(gUp + k0, &Bu[b][(w * 64) * 8]);
  };
  auto compute = [&](int b) {
    bf16x8 af[4], bg2[2], bu2[2];
#pragma unroll
    for (int i = 0; i < 4; i++)
      af[i] = *(const bf16x8*)&Al[b][(wm * 64 + i * 16 + r16) * 32 + ch];
#pragma unroll
    for (int j = 0; j < 2; j++) {
      bg2[j] = *(const bf16x8*)&Bg[b][(wn * 32 + j * 16 + r16) * 32 + ch];
      bu2[j] = *(const bf16x8*)&Bu[b][(wn * 32 + j * 16 + r16) * 32 + ch];
    }
#pragma unroll
    for (int i = 0; i < 4; i++)
#pragma unroll
      for (int j = 0; j < 2; j++) {
        accg[i][j] = __builtin_amdgcn_mfma_f32_16x16x32_bf16(af[i], bg2[j], accg[i][j], 0, 0, 0);
        accu[i][j] = __builtin_amdgcn_mfma_f32_16x16x32_bf16(af[i], bu2[j], accu[i][j], 0, 0, 0);
      }
  };

  stage(0, 0);
  stage(32, 1);
#pragma unroll 1
  for (int p = 0; p < 32; p++) {
    if (p < 30) {
      asm volatile("s_waitcnt vmcnt(4)" ::: "memory");   // oldest stage landed
    } else {
      asm volatile("s_waitcnt vmcnt(0)" ::: "memory");   // tail: drain all
    }
    __builtin_amdgcn_s_barrier();
    if (p + 2 < 32) stage((p + 2) * 32, (p + 2) % 3);
    compute(p % 3);
  }

#pragma unroll
  for (int i = 0; i < 4; i++) {
#pragma unroll
    for (int j = 0; j < 2; j++) {
      const int col = n0 + wn * 32 + j * 16 + r16;
#pragma unroll
      for (int r = 0; r < 4; r++) {
        int pos = m0 + wm * 64 + i * 16 + q * 4 + r;
        if (pos < count) {
          float g = accg[i][j][r], u = accu[i][j][r];
          float h = u / (1.f + __expf(-g));
          hid[(size_t)(hidbase + pos) * IDIM + col] = f2bf(h);
        }
      }
    }
  }
}

// ---------------- fused down GEMM (z=0..7 routed, z=8 shared) ---------------
// BM=128, BN=128, BK=32. 3-stage pipeline as above. All atomicAdd (out
// pre-initialized with residual by convert_x).
__global__ __launch_bounds__(256) void down_f(
    const unsigned short* __restrict__ hid,
    const unsigned short* __restrict__ downT,
    float* __restrict__ out,
    const int* __restrict__ cnt, const int* __restrict__ list,
    const float* __restrict__ wgt) {
  __shared__ unsigned short Al[3][128 * 32];  // 24 KB
  __shared__ unsigned short Bl[3][128 * 32];  // 24 KB

  const int tid = threadIdx.x;
  const int lane = tid & 63;
  const int w = tid >> 6;
  const int wm = w >> 1, wn = w & 1;
  const int z = blockIdx.z;
  const int m0 = blockIdx.y * 128;
  const int n0 = blockIdx.x * 128;

  int count, abase;
  if (z < EDIM) {
    count = cnt[z];
    if (m0 >= count) return;
    int off = 0;
#pragma unroll
    for (int i = 0; i < EDIM; i++) off += (i < z) ? cnt[i] : 0;
    abase = off;
  } else {
    count = T_TOK;
    abase = HID_SHARED_BASE;
  }
  const unsigned short* wd = downT + (size_t)z * IDIM * HDIM;

  const unsigned short *gA[2], *gBp[2];
#pragma unroll
  for (int j = 0; j < 2; j++) {
    const int s = w * 128 + j * 64 + lane;
    const int row = s >> 2;
    const int g = (s & 3) ^ ((row + (row >> 2)) & 3);
    gA[j]  = hid + (size_t)(abase + m0 + row) * IDIM + g * 8;
    gBp[j] = wd + (size_t)(n0 + row) * IDIM + g * 8;
  }

  f32x4 acc[4][4];
  const f32x4 z4 = {0.f, 0.f, 0.f, 0.f};
#pragma unroll
  for (int i = 0; i < 4; i++)
#pragma unroll
    for (int j = 0; j < 4; j++) acc[i][j] = z4;

  const int q = lane >> 4;
  const int r16 = lane & 15;
  const int ch = (q ^ ((r16 + (r16 >> 2)) & 3)) * 8;

  auto stage = [&](int k0, int b) {
    GLD16(gA[0] + k0,  &Al[b][(w * 128) * 8]);
    GLD16(gA[1] + k0,  &Al[b][(w * 128 + 64) * 8]);
    GLD16(gBp[0] + k0, &Bl[b][(w * 128) * 8]);
    GLD16(gBp[1] + k0, &Bl[b][(w * 128 + 64) * 8]);
  };
  auto compute = [&](int b) {
    bf16x8 af[4], bf4[4];
#pragma unroll
    for (int i = 0; i < 4; i++)
      af[i] = *(const bf16x8*)&Al[b][(wm * 64 + i * 16 + r16) * 32 + ch];
#pragma unroll
    for (int j = 0; j < 4; j++)
      bf4[j] = *(const bf16x8*)&Bl[b][(wn * 64 + j * 16 + r16) * 32 + ch];
#pragma unroll
    for (int i = 0; i < 4; i++)
#pragma unroll
      for (int j = 0; j < 4; j++)
        acc[i][j] = __builtin_amdgcn_mfma_f32_16x16x32_bf16(af[i], bf4[j], acc[i][j], 0, 0, 0);
  };

  stage(0, 0);
  stage(32, 1);
#pragma unroll 1
  for (int p = 0; p < 32; p++) {
    if (p < 30) {
      asm volatile("s_waitcnt vmcnt(4)" ::: "memory");
    } else {
      asm volatile("s_waitcnt vmcnt(0)" ::: "memory");
    }
    __builtin_amdgcn_s_barrier();
    if (p + 2 < 32) stage((p + 2) * 32, (p + 2) % 3);
    compute(p % 3);
  }

#pragma unroll
  for (int i = 0; i < 4; i++) {
    int toks[4]; float ws4[4];
#pragma unroll
    for (int r = 0; r < 4; r++) {
      int pos = m0 + wm * 64 + i * 16 + q * 4 + r;
      if (z < EDIM) {
        bool ok = pos < count;
        toks[r] = ok ? list[z * T_TOK + pos] : -1;
        ws4[r] = ok ? wgt[z * T_TOK + pos] : 0.f;
      } else {
        toks[r] = pos; ws4[r] = 1.f;
      }
    }
#pragma unroll
    for (int j = 0; j < 4; j++) {
      const int col = n0 + wn * 64 + j * 16 + r16;
#pragma unroll
      for (int r = 0; r < 4; r++) {
        if (toks[r] >= 0)
          atomicAdd(&out[(size_t)toks[r] * HDIM + col], ws4[r] * acc[i][j][r]);
      }
    }
  }
}

extern "C" void kernel_launch(void* const* d_in, const int* in_sizes, int n_in,
                              void* d_out, int out_size, void* d_ws, size_t ws_size,
                              hipStream_t stream) {
  const float* x  = (const float*)d_in[0];
  const float* rw = (const float*)d_in[1];
  const float* sg = (const float*)d_in[2];
  const float* su = (const float*)d_in[3];
  const float* sd = (const float*)d_in[4];
  const float* eg = (const float*)d_in[5];
  const float* eu = (const float*)d_in[6];
  const float* ed = (const float*)d_in[7];
  float* out = (float*)d_out;

  char* ws = (char*)d_ws;
  unsigned short* xb  = (unsigned short*)ws;                          // 4096x1024 bf16
  unsigned short* hid = xb + (size_t)T_TOK * HDIM;                    // 12416x1024 bf16
  int*   cnt  = (int*)(hid + (size_t)(HID_SHARED_BASE + T_TOK) * IDIM);
  int*   list = cnt + 16;
  float* wgt  = (float*)(list + EDIM * T_TOK);
  unsigned short* wT    = (unsigned short*)(wgt + EDIM * T_TOK);      // 27 x 1M bf16
  unsigned short* gateT = wT;
  unsigned short* upT   = wT + (size_t)9 * 1048576;
  unsigned short* downT = wT + (size_t)18 * 1048576;

  zero_cnt<<<1, 64, 0, stream>>>(cnt);
  convert_x<<<(T_TOK * HDIM) / 1024, 256, 0, stream>>>(
      (const float4*)x, (ushort4*)xb, (float4*)out);
  router2<<<T_TOK / 16, 256, 0, stream>>>(x, rw, cnt, list, wgt);

  SrcPtrs S; S.p[0] = sg; S.p[1] = su; S.p[2] = sd; S.p[3] = eg; S.p[4] = eu; S.p[5] = ed;
  transpose_all<<<dim3(16, 16, 27), 256, 0, stream>>>(S, wT);

  gateup_f<<<dim3(IDIM / 64, 32, 9), 256, 0, stream>>>(xb, gateT, upT, hid, cnt, list);
  down_f<<<dim3(HDIM / 128, 32, 9), 256, 0, stream>>>(hid, downT, out, cnt, list, wgt);
}

// Round 6
// 378.385 us; speedup vs baseline: 2.0071x; 1.0004x over previous
//
#include <hip/hip_runtime.h>
#include <hip/hip_bf16.h>

#define T_TOK 4096
#define HDIM 1024
#define IDIM 1024
#define EDIM 8
#define HID_SHARED_BASE 8320   // routed hid rows [0,8320); shared at [8320,12416)

typedef __attribute__((ext_vector_type(8))) short bf16x8;
typedef __attribute__((ext_vector_type(4))) float f32x4;

static __device__ __forceinline__ unsigned short f2bf(float f) {
  union { float f; unsigned int u; } v; v.f = f;
  unsigned int u = v.u;
  unsigned int r = u + 0x7FFFu + ((u >> 16) & 1u);   // RTNE
  return (unsigned short)(r >> 16);
}
static __device__ __forceinline__ float bf2f(unsigned short s) {
  union { unsigned int u; float f; } v; v.u = ((unsigned int)s) << 16;
  return v.f;
}

// async global->LDS, 16B per lane; lds dest = wave-uniform base + lane*16
#define GLD16(g, l) __builtin_amdgcn_global_load_lds( \
    (const __attribute__((address_space(1))) void*)(g), \
    (__attribute__((address_space(3))) void*)(l), 16, 0, 0)

// ------- x fp32 -> bf16 (+optional out=residual init, + cnt zeroing) -------
__global__ __launch_bounds__(256) void convert_x(const float4* __restrict__ x4,
                                                 ushort4* __restrict__ xb4,
                                                 float4* __restrict__ out4,
                                                 int* __restrict__ cnt, int initOut) {
  int i = blockIdx.x * 256 + threadIdx.x;
  if (blockIdx.x == 0 && threadIdx.x < 16) cnt[threadIdx.x] = 0;
  float4 v = x4[i];
  if (initOut) out4[i] = v;
  ushort4 o;
  o.x = f2bf(v.x); o.y = f2bf(v.y); o.z = f2bf(v.z); o.w = f2bf(v.w);
  xb4[i] = o;
}

// ---------------- all 27 weight matrices: fp32 [K][N] -> bf16 [N][K] -------
// Register transpose, no LDS. Per thread: 8 rows x 4 cols micro-tile.
// grid (8, 16, 27): x -> 128-col block, y -> 64-row block.
struct SrcPtrs { const float* p[6]; };

__global__ __launch_bounds__(256) void transpose_all(SrcPtrs S,
                                                     unsigned short* __restrict__ dstBase) {
  const int z = blockIdx.z;
  const float* src; int dz;
  if (z == 0)      { src = S.p[0];                              dz = 8;  }
  else if (z == 1) { src = S.p[1];                              dz = 17; }
  else if (z == 2) { src = S.p[2];                              dz = 26; }
  else if (z < 11) { src = S.p[3] + (size_t)(z - 3)  * 1048576; dz = z - 3; }
  else if (z < 19) { src = S.p[4] + (size_t)(z - 11) * 1048576; dz = 9 + (z - 11); }
  else             { src = S.p[5] + (size_t)(z - 19) * 1048576; dz = 18 + (z - 19); }
  unsigned short* dst = dstBase + (size_t)dz * 1048576;

  const int tid = threadIdx.x;
  const int rid = tid & 7;          // 8 row sub-blocks
  const int cid = tid >> 3;         // 0..31 col ids
  const int r = blockIdx.y * 64 + rid * 8;   // 8 consecutive rows
  const int c = blockIdx.x * 128 + cid * 4;  // 4 consecutive cols

  float4 v[8];
#pragma unroll
  for (int i = 0; i < 8; i++)
    v[i] = *(const float4*)&src[(size_t)(r + i) * 1024 + c];

#pragma unroll
  for (int j = 0; j < 4; j++) {
    unsigned short o[8];
    o[0] = f2bf(v[0][j]); o[1] = f2bf(v[1][j]);
    o[2] = f2bf(v[2][j]); o[3] = f2bf(v[3][j]);
    o[4] = f2bf(v[4][j]); o[5] = f2bf(v[5][j]);
    o[6] = f2bf(v[6][j]); o[7] = f2bf(v[7][j]);
    *(bf16x8*)&dst[(size_t)(c + j) * 1024 + r] = *(const bf16x8*)o;
  }
}

// ---------------- router: tiled fp32 logits + softmax + top2 ----------------
// list entry encodes (token<<1)|slot so down can scatter without atomics.
__global__ __launch_bounds__(256) void router2(
    const float* __restrict__ x, const float* __restrict__ rw,
    int* __restrict__ cnt, int* __restrict__ list, float* __restrict__ wgt) {
  __shared__ float rwT[1024 * 8];
  const int tid = threadIdx.x;
#pragma unroll
  for (int c = 0; c < 4; c++) {
    const int h = c * 256 + tid;
    float v[8];
#pragma unroll
    for (int e = 0; e < EDIM; e++) v[e] = rw[e * 1024 + h];
    *(float4*)&rwT[h * 8]     = make_float4(v[0], v[1], v[2], v[3]);
    *(float4*)&rwT[h * 8 + 4] = make_float4(v[4], v[5], v[6], v[7]);
  }
  __syncthreads();

  const int tt = tid >> 4;
  const int pp = tid & 15;
  const int t = blockIdx.x * 16 + tt;
  const float* xr = x + (size_t)t * HDIM;

  float a[EDIM];
#pragma unroll
  for (int e = 0; e < EDIM; e++) a[e] = 0.f;

#pragma unroll 8
  for (int i = 0; i < 64; i++) {
    const int h = pp + 16 * i;
    const float xs = xr[h];
    const float4 r0 = *(const float4*)&rwT[h * 8];
    const float4 r1 = *(const float4*)&rwT[h * 8 + 4];
    a[0] += xs * r0.x; a[1] += xs * r0.y; a[2] += xs * r0.z; a[3] += xs * r0.w;
    a[4] += xs * r1.x; a[5] += xs * r1.y; a[6] += xs * r1.z; a[7] += xs * r1.w;
  }
#pragma unroll
  for (int s = 1; s < 16; s <<= 1) {
#pragma unroll
    for (int e = 0; e < EDIM; e++) a[e] += __shfl_xor(a[e], s, 16);
  }
  if (pp == 0) {
    float m = a[0];
#pragma unroll
    for (int e = 1; e < EDIM; e++) m = fmaxf(m, a[e]);
    float p[EDIM]; float s = 0.f;
#pragma unroll
    for (int e = 0; e < EDIM; e++) { p[e] = expf(a[e] - m); s += p[e]; }
    float inv = 1.f / s;
    int e1 = 0; float b1 = p[0];
#pragma unroll
    for (int e = 1; e < EDIM; e++) if (p[e] > b1) { b1 = p[e]; e1 = e; }
    int e2 = -1; float b2 = -1.f;
#pragma unroll
    for (int e = 0; e < EDIM; e++) if (e != e1 && p[e] > b2) { b2 = p[e]; e2 = e; }
    int pos1 = atomicAdd(&cnt[e1], 1);
    list[e1 * T_TOK + pos1] = (t << 1);      wgt[e1 * T_TOK + pos1] = b1 * inv;
    int pos2 = atomicAdd(&cnt[e2], 1);
    list[e2 * T_TOK + pos2] = (t << 1) | 1;  wgt[e2 * T_TOK + pos2] = b2 * inv;
  }
}

// ---------------- fused gate/up GEMM (z=0..7 routed, z=8 shared) ------------
// BM=128, BN=64, BK=32. 3-stage LDS pipeline, raw s_barrier + manual vmcnt.
__global__ __launch_bounds__(256) void gateup_f(
    const unsigned short* __restrict__ xb,
    const unsigned short* __restrict__ gateT,
    const unsigned short* __restrict__ upT,
    unsigned short* __restrict__ hid,
    const int* __restrict__ cnt, const int* __restrict__ list) {
  __shared__ unsigned short Al[3][128 * 32];  // 24 KB
  __shared__ unsigned short Bg[3][64 * 32];   // 12 KB
  __shared__ unsigned short Bu[3][64 * 32];   // 12 KB

  const int tid = threadIdx.x;
  const int lane = tid & 63;
  const int w = tid >> 6;
  const int wm = w >> 1, wn = w & 1;
  const int z = blockIdx.z;
  const int m0 = blockIdx.y * 128;
  const int n0 = blockIdx.x * 64;

  int count, hidbase;
  if (z < EDIM) {
    count = cnt[z];
    if (m0 >= count) return;
    int off = 0;
#pragma unroll
    for (int i = 0; i < EDIM; i++) off += (i < z) ? cnt[i] : 0;
    hidbase = off;
  } else {
    count = T_TOK;
    hidbase = HID_SHARED_BASE;
  }
  const unsigned short* wg = gateT + (size_t)z * HDIM * IDIM;
  const unsigned short* wu = upT   + (size_t)z * HDIM * IDIM;

  const unsigned short* gA[2];
#pragma unroll
  for (int j = 0; j < 2; j++) {
    const int s = w * 128 + j * 64 + lane;
    const int row = s >> 2;
    const int g = (s & 3) ^ ((row + (row >> 2)) & 3);
    int tok;
    if (z < EDIM) {
      int p = m0 + row; if (p >= count) p = count - 1;
      tok = list[z * T_TOK + p] >> 1;
    } else tok = m0 + row;
    gA[j] = xb + (size_t)tok * HDIM + g * 8;
  }
  const int sB = w * 64 + lane;
  const int rowB = sB >> 2;
  const int gB = (sB & 3) ^ ((rowB + (rowB >> 2)) & 3);
  const unsigned short* gGp = wg + (size_t)(n0 + rowB) * HDIM + gB * 8;
  const unsigned short* gUp = wu + (size_t)(n0 + rowB) * HDIM + gB * 8;

  f32x4 accg[4][2], accu[4][2];
  const f32x4 z4 = {0.f, 0.f, 0.f, 0.f};
#pragma unroll
  for (int i = 0; i < 4; i++)
#pragma unroll
    for (int j = 0; j < 2; j++) { accg[i][j] = z4; accu[i][j] = z4; }

  const int q = lane >> 4;
  const int r16 = lane & 15;
  const int ch = (q ^ ((r16 + (r16 >> 2)) & 3)) * 8;

  auto stage = [&](int k0, int b) {
    GLD16(gA[0] + k0, &Al[b][(w * 128) * 8]);
    GLD16(gA[1] + k0, &Al[b][(w * 128 + 64) * 8]);
    GLD16(gGp + k0, &Bg[b][(w * 64) * 8]);
    GLD16(gUp + k0, &Bu[b][(w * 64) * 8]);
  };
  auto compute = [&](int b) {
    bf16x8 af[4], bg2[2], bu2[2];
#pragma unroll
    for (int i = 0; i < 4; i++)
      af[i] = *(const bf16x8*)&Al[b][(wm * 64 + i * 16 + r16) * 32 + ch];
#pragma unroll
    for (int j = 0; j < 2; j++) {
      bg2[j] = *(const bf16x8*)&Bg[b][(wn * 32 + j * 16 + r16) * 32 + ch];
      bu2[j] = *(const bf16x8*)&Bu[b][(wn * 32 + j * 16 + r16) * 32 + ch];
    }
#pragma unroll
    for (int i = 0; i < 4; i++)
#pragma unroll
      for (int j = 0; j < 2; j++) {
        accg[i][j] = __builtin_amdgcn_mfma_f32_16x16x32_bf16(af[i], bg2[j], accg[i][j], 0, 0, 0);
        accu[i][j] = __builtin_amdgcn_mfma_f32_16x16x32_bf16(af[i], bu2[j], accu[i][j], 0, 0, 0);
      }
  };

  stage(0, 0);
  stage(32, 1);
#pragma unroll 1
  for (int p = 0; p < 32; p++) {
    if (p < 30) {
      asm volatile("s_waitcnt vmcnt(4)" ::: "memory");
    } else {
      asm volatile("s_waitcnt vmcnt(0)" ::: "memory");
    }
    __builtin_amdgcn_s_barrier();
    if (p + 2 < 32) stage((p + 2) * 32, (p + 2) % 3);
    compute(p % 3);
  }

#pragma unroll
  for (int i = 0; i < 4; i++) {
#pragma unroll
    for (int j = 0; j < 2; j++) {
      const int col = n0 + wn * 32 + j * 16 + r16;
#pragma unroll
      for (int r = 0; r < 4; r++) {
        int pos = m0 + wm * 64 + i * 16 + q * 4 + r;
        if (pos < count) {
          float g = accg[i][j][r], u = accu[i][j][r];
          float h = u / (1.f + __expf(-g));
          hid[(size_t)(hidbase + pos) * IDIM + col] = f2bf(h);
        }
      }
    }
  }
}

// ---------------- fused down GEMM (z=0..7 routed, z=8 shared) ---------------
// Epilogue: useR -> plain bf16 stores to R[t][slot][col]; else atomicAdd(out).
__global__ __launch_bounds__(256) void down_f(
    const unsigned short* __restrict__ hid,
    const unsigned short* __restrict__ downT,
    float* __restrict__ out, unsigned short* __restrict__ R, int useR,
    const int* __restrict__ cnt, const int* __restrict__ list,
    const float* __restrict__ wgt) {
  __shared__ unsigned short Al[3][128 * 32];  // 24 KB
  __shared__ unsigned short Bl[3][128 * 32];  // 24 KB

  const int tid = threadIdx.x;
  const int lane = tid & 63;
  const int w = tid >> 6;
  const int wm = w >> 1, wn = w & 1;
  const int z = blockIdx.z;
  const int m0 = blockIdx.y * 128;
  const int n0 = blockIdx.x * 128;

  int count, abase;
  if (z < EDIM) {
    count = cnt[z];
    if (m0 >= count) return;
    int off = 0;
#pragma unroll
    for (int i = 0; i < EDIM; i++) off += (i < z) ? cnt[i] : 0;
    abase = off;
  } else {
    count = T_TOK;
    abase = HID_SHARED_BASE;
  }
  const unsigned short* wd = downT + (size_t)z * IDIM * HDIM;

  const unsigned short *gA[2], *gBp[2];
#pragma unroll
  for (int j = 0; j < 2; j++) {
    const int s = w * 128 + j * 64 + lane;
    const int row = s >> 2;
    const int g = (s & 3) ^ ((row + (row >> 2)) & 3);
    gA[j]  = hid + (size_t)(abase + m0 + row) * IDIM + g * 8;
    gBp[j] = wd + (size_t)(n0 + row) * IDIM + g * 8;
  }

  f32x4 acc[4][4];
  const f32x4 z4 = {0.f, 0.f, 0.f, 0.f};
#pragma unroll
  for (int i = 0; i < 4; i++)
#pragma unroll
    for (int j = 0; j < 4; j++) acc[i][j] = z4;

  const int q = lane >> 4;
  const int r16 = lane & 15;
  const int ch = (q ^ ((r16 + (r16 >> 2)) & 3)) * 8;

  auto stage = [&](int k0, int b) {
    GLD16(gA[0] + k0,  &Al[b][(w * 128) * 8]);
    GLD16(gA[1] + k0,  &Al[b][(w * 128 + 64) * 8]);
    GLD16(gBp[0] + k0, &Bl[b][(w * 128) * 8]);
    GLD16(gBp[1] + k0, &Bl[b][(w * 128 + 64) * 8]);
  };
  auto compute = [&](int b) {
    bf16x8 af[4], bf4[4];
#pragma unroll
    for (int i = 0; i < 4; i++)
      af[i] = *(const bf16x8*)&Al[b][(wm * 64 + i * 16 + r16) * 32 + ch];
#pragma unroll
    for (int j = 0; j < 4; j++)
      bf4[j] = *(const bf16x8*)&Bl[b][(wn * 64 + j * 16 + r16) * 32 + ch];
#pragma unroll
    for (int i = 0; i < 4; i++)
#pragma unroll
      for (int j = 0; j < 4; j++)
        acc[i][j] = __builtin_amdgcn_mfma_f32_16x16x32_bf16(af[i], bf4[j], acc[i][j], 0, 0, 0);
  };

  stage(0, 0);
  stage(32, 1);
#pragma unroll 1
  for (int p = 0; p < 32; p++) {
    if (p < 30) {
      asm volatile("s_waitcnt vmcnt(4)" ::: "memory");
    } else {
      asm volatile("s_waitcnt vmcnt(0)" ::: "memory");
    }
    __builtin_amdgcn_s_barrier();
    if (p + 2 < 32) stage((p + 2) * 32, (p + 2) % 3);
    compute(p % 3);
  }

#pragma unroll
  for (int i = 0; i < 4; i++) {
    int toks[4]; int slot[4]; float ws4[4];
#pragma unroll
    for (int r = 0; r < 4; r++) {
      int pos = m0 + wm * 64 + i * 16 + q * 4 + r;
      if (z < EDIM) {
        bool ok = pos < count;
        int v = ok ? list[z * T_TOK + pos] : -2;
        toks[r] = v >> 1; slot[r] = v & 1;
        ws4[r] = ok ? wgt[z * T_TOK + pos] : 0.f;
      } else {
        toks[r] = pos; slot[r] = 2; ws4[r] = 1.f;
      }
    }
#pragma unroll
    for (int j = 0; j < 4; j++) {
      const int col = n0 + wn * 64 + j * 16 + r16;
#pragma unroll
      for (int r = 0; r < 4; r++) {
        if (toks[r] >= 0) {
          float v = ws4[r] * acc[i][j][r];
          if (useR) {
            R[((size_t)toks[r] * 3 + slot[r]) * HDIM + col] = f2bf(v);
          } else {
            atomicAdd(&out[(size_t)toks[r] * HDIM + col], v);
          }
        }
      }
    }
  }
}

// ---------------- final combine: out = x + R0 + R1 + R2 ---------------------
__global__ __launch_bounds__(256) void combine_k(const float4* __restrict__ x4,
                                                 const unsigned short* __restrict__ R,
                                                 float4* __restrict__ out4) {
  const int i8 = blockIdx.x * 256 + threadIdx.x;   // 8-element chunk id
  const int t = i8 >> 7;
  const int c8 = (i8 & 127) * 8;
  const unsigned short* r0 = R + ((size_t)t * 3) * 1024 + c8;
  float s[8];
#pragma unroll
  for (int k = 0; k < 8; k++) s[k] = 0.f;
#pragma unroll
  for (int sl = 0; sl < 3; sl++) {
    bf16x8 v = *(const bf16x8*)(r0 + sl * 1024);
#pragma unroll
    for (int k = 0; k < 8; k++) s[k] += bf2f(((const unsigned short*)&v)[k]);
  }
  float4 a = x4[i8 * 2], b = x4[i8 * 2 + 1];
  a.x += s[0]; a.y += s[1]; a.z += s[2]; a.w += s[3];
  b.x += s[4]; b.y += s[5]; b.z += s[6]; b.w += s[7];
  out4[i8 * 2] = a;
  out4[i8 * 2 + 1] = b;
}

extern "C" void kernel_launch(void* const* d_in, const int* in_sizes, int n_in,
                              void* d_out, int out_size, void* d_ws, size_t ws_size,
                              hipStream_t stream) {
  const float* x  = (const float*)d_in[0];
  const float* rw = (const float*)d_in[1];
  const float* sg = (const float*)d_in[2];
  const float* su = (const float*)d_in[3];
  const float* sd = (const float*)d_in[4];
  const float* eg = (const float*)d_in[5];
  const float* eu = (const float*)d_in[6];
  const float* ed = (const float*)d_in[7];
  float* out = (float*)d_out;

  char* ws = (char*)d_ws;
  unsigned short* xb  = (unsigned short*)ws;                          // 8 MB
  unsigned short* hid = xb + (size_t)T_TOK * HDIM;                    // 25.4 MB
  int*   cnt  = (int*)(hid + (size_t)(HID_SHARED_BASE + T_TOK) * IDIM);
  int*   list = cnt + 16;
  float* wgt  = (float*)(list + EDIM * T_TOK);
  unsigned short* wT    = (unsigned short*)(wgt + EDIM * T_TOK);      // 54 MB
  unsigned short* gateT = wT;
  unsigned short* upT   = wT + (size_t)9 * 1048576;
  unsigned short* downT = wT + (size_t)18 * 1048576;
  unsigned short* R = wT + (size_t)27 * 1048576;                      // 25 MB
  size_t need = ((char*)(R + (size_t)T_TOK * 3 * HDIM)) - ws;
  const int useR = (ws_size >= need) ? 1 : 0;

  convert_x<<<(T_TOK * HDIM) / 1024, 256, 0, stream>>>(
      (const float4*)x, (ushort4*)xb, (float4*)out, cnt, useR ? 0 : 1);
  router2<<<T_TOK / 16, 256, 0, stream>>>(x, rw, cnt, list, wgt);

  SrcPtrs S; S.p[0] = sg; S.p[1] = su; S.p[2] = sd; S.p[3] = eg; S.p[4] = eu; S.p[5] = ed;
  transpose_all<<<dim3(8, 16, 27), 256, 0, stream>>>(S, wT);

  gateup_f<<<dim3(IDIM / 64, 32, 9), 256, 0, stream>>>(xb, gateT, upT, hid, cnt, list);
  down_f<<<dim3(HDIM / 128, 32, 9), 256, 0, stream>>>(hid, downT, out, R, useR,
                                                      cnt, list, wgt);
  if (useR) {
    combine_k<<<(T_TOK * HDIM / 8) / 256, 256, 0, stream>>>(
        (const float4*)x, R, (float4*)out);
  }
}